// Round 1
// baseline (3992.113 us; speedup 1.0000x reference)
//
#include <hip/hip_runtime.h>
#include <math.h>

#define NTOK 32768

// d_out offsets (in floats)
#define OFF_CENT 0
#define OFF_SE   131072
#define OFF_WC   16908288
#define OFF_SC   16973824
#define OFF_OT   17039360
#define OFF_CT   17072128
#define OFF_OI   17072640
#define OFF_CI   17105408

__device__ __forceinline__ float dot4(float4 a, float4 b){
    return a.x*b.x + a.y*b.y + a.z*b.z + a.w*b.w;
}

// ---------------- centroids: tanh + c2 ----------------
__global__ __launch_bounds__(64) void k_cent(const float* __restrict__ raw,
                                             float* __restrict__ out,
                                             float* __restrict__ c2)
{
    int c = blockIdx.x, l = threadIdx.x;
    float4 v = *(const float4*)(raw + (size_t)c*256 + l*4);
    float4 t;
    t.x = tanhf(v.x); t.y = tanhf(v.y); t.z = tanhf(v.z); t.w = tanhf(v.w);
    *(float4*)(out + OFF_CENT + (size_t)c*256 + l*4) = t;
    float s = dot4(t, t);
    #pragma unroll
    for (int off = 32; off > 0; off >>= 1) s += __shfl_down(s, off);
    if (l == 0) c2[c] = s;
}

// ---------------- word_class fill ----------------
__global__ __launch_bounds__(256) void k_wc(float* __restrict__ out)
{
    int g = blockIdx.x*256 + threadIdx.x;          // 16384 float4s
    float v = (g*4 < NTOK) ? 0.f : 1.f;
    float4* p = (float4*)(out + OFF_WC);
    p[g] = make_float4(v, v, v, v);
}

// ---------------- fp32 GEMM + tanh: C = tanh(A[M,K] @ B[K,N]) ----------------
// BM=BN=128, BK=16, 256 threads, 8x8 micro-tile
__global__ __launch_bounds__(256, 2) void k_gemm_tanh(
    const float* __restrict__ A, const float* __restrict__ B, float* __restrict__ C,
    int M, int N, int K)
{
    __shared__ float As[16][132];   // padded: store-transposed A tile
    __shared__ float Bs[16][128];

    const int tid = threadIdx.x;
    const int bx = blockIdx.x, by = blockIdx.y;
    const int tx = tid & 15, ty = tid >> 4;
    const int ar0 = tid >> 2, ac4 = (tid & 3) * 4;     // A-tile load coords
    const int bk0 = tid >> 5, bn4 = (tid & 31) * 4;    // B-tile load coords

    const float* Ab = A + (size_t)(by*128) * K;
    const float* Bb = B + bx*128;

    float acc[8][8];
    #pragma unroll
    for (int i = 0; i < 8; ++i)
        #pragma unroll
        for (int j = 0; j < 8; ++j) acc[i][j] = 0.f;

    for (int kt = 0; kt < K; kt += 16) {
        float4 a0 = *(const float4*)(Ab + (size_t)ar0*K       + kt + ac4);
        float4 a1 = *(const float4*)(Ab + (size_t)(ar0+64)*K  + kt + ac4);
        float4 b0 = *(const float4*)(Bb + (size_t)(kt+bk0)*N   + bn4);
        float4 b1 = *(const float4*)(Bb + (size_t)(kt+bk0+8)*N + bn4);
        __syncthreads();
        As[ac4+0][ar0] = a0.x; As[ac4+1][ar0] = a0.y;
        As[ac4+2][ar0] = a0.z; As[ac4+3][ar0] = a0.w;
        As[ac4+0][ar0+64] = a1.x; As[ac4+1][ar0+64] = a1.y;
        As[ac4+2][ar0+64] = a1.z; As[ac4+3][ar0+64] = a1.w;
        *(float4*)&Bs[bk0  ][bn4] = b0;
        *(float4*)&Bs[bk0+8][bn4] = b1;
        __syncthreads();
        #pragma unroll
        for (int k = 0; k < 16; ++k) {
            float4 x0 = *(const float4*)&As[k][ty*4];
            float4 x1 = *(const float4*)&As[k][ty*4 + 64];
            float4 y0 = *(const float4*)&Bs[k][tx*4];
            float4 y1 = *(const float4*)&Bs[k][tx*4 + 64];
            float xa[8] = {x0.x,x0.y,x0.z,x0.w, x1.x,x1.y,x1.z,x1.w};
            float yb[8] = {y0.x,y0.y,y0.z,y0.w, y1.x,y1.y,y1.z,y1.w};
            #pragma unroll
            for (int i = 0; i < 8; ++i)
                #pragma unroll
                for (int j = 0; j < 8; ++j)
                    acc[i][j] += xa[i] * yb[j];
        }
    }

    const size_t cb = (size_t)(by*128) * N + bx*128;
    #pragma unroll
    for (int i = 0; i < 8; ++i) {
        int row = ty*4 + (i & 3) + ((i >> 2) << 6);
        float4 o;
        o.x = tanhf(acc[i][0]); o.y = tanhf(acc[i][1]);
        o.z = tanhf(acc[i][2]); o.w = tanhf(acc[i][3]);
        *(float4*)(C + cb + (size_t)row*N + tx*4) = o;
        o.x = tanhf(acc[i][4]); o.y = tanhf(acc[i][5]);
        o.z = tanhf(acc[i][6]); o.w = tanhf(acc[i][7]);
        *(float4*)(C + cb + (size_t)row*N + tx*4 + 64) = o;
    }
}

// ---------------- assignment: argmin_k (c2 + e2 - 2*dot) ----------------
// block: 64 tokens, loop over 8 tiles of 64 centroids. LDS = 128 KiB exactly.
__global__ __launch_bounds__(256) void k_assign(
    const float* __restrict__ out_ro,   // d_out (se + centroids)
    const float* __restrict__ c2,
    int* __restrict__ sc,
    float* __restrict__ out_w)          // d_out (sense_class)
{
    const int modal = blockIdx.y;
    const int tok0 = blockIdx.x * 64;
    const float* se   = out_ro + OFF_SE + (size_t)modal * NTOK * 256;
    const float* cent = out_ro + OFF_CENT;

    __shared__ float4 se4[64][64];
    __shared__ float4 ct4[64][64];

    const int tid = threadIdx.x;
    const int tt = tid & 15, cc = tid >> 4;

    // load se tile (coalesced 1KB rows), XOR-swizzled by token>>2
    {
        int rbase = tid >> 6;      // 0..3
        int d4 = tid & 63;
        #pragma unroll
        for (int i = 0; i < 16; ++i) {
            int t = i*4 + rbase;
            float4 v = *(const float4*)(se + (size_t)(tok0 + t)*256 + d4*4);
            se4[t][d4 ^ (t >> 2)] = v;
        }
    }
    __syncthreads();

    // per-thread e2 for its 4 tokens
    float e2r[4];
    #pragma unroll
    for (int k2 = 0; k2 < 4; ++k2) {
        float s = 0.f;
        for (int d4 = 0; d4 < 64; ++d4) {
            float4 v = se4[4*tt + k2][d4 ^ tt];
            s += dot4(v, v);
        }
        e2r[k2] = s;
    }

    float bd[4]; int bi[4];
    #pragma unroll
    for (int k2 = 0; k2 < 4; ++k2) { bd[k2] = 3.4e38f; bi[k2] = 0; }

    for (int ctile = 0; ctile < 8; ++ctile) {
        int c0 = ctile * 64;
        {
            int rbase = tid >> 6;
            int d4 = tid & 63;
            #pragma unroll
            for (int i = 0; i < 16; ++i) {
                int r = i*4 + rbase;
                float4 v = *(const float4*)(cent + (size_t)(c0 + r)*256 + d4*4);
                ct4[r][d4 ^ (r >> 2)] = v;
            }
        }
        __syncthreads();

        float accd[4][4];
        #pragma unroll
        for (int a = 0; a < 4; ++a)
            #pragma unroll
            for (int b = 0; b < 4; ++b) accd[a][b] = 0.f;

        for (int d4 = 0; d4 < 64; ++d4) {
            float4 sv[4], cv[4];
            #pragma unroll
            for (int k2 = 0; k2 < 4; ++k2) sv[k2] = se4[4*tt + k2][d4 ^ tt];
            #pragma unroll
            for (int j = 0; j < 4; ++j)    cv[j]  = ct4[4*cc + j ][d4 ^ cc];
            #pragma unroll
            for (int k2 = 0; k2 < 4; ++k2)
                #pragma unroll
                for (int j = 0; j < 4; ++j)
                    accd[k2][j] += dot4(sv[k2], cv[j]);
        }

        #pragma unroll
        for (int j = 0; j < 4; ++j) {
            int cidx = c0 + 4*cc + j;
            float cj = c2[cidx];
            #pragma unroll
            for (int k2 = 0; k2 < 4; ++k2) {
                float d = cj + e2r[k2] - 2.f * accd[k2][j];
                if (d < bd[k2]) { bd[k2] = d; bi[k2] = cidx; }  // first-occurrence: ascending cidx
            }
        }
        __syncthreads();   // protect ct4 before next overwrite / reuse
    }

    // cross-thread reduce via overlay on ct4 (no longer needed)
    float* red_d = (float*)ct4;
    int*   red_i = (int*)ct4 + 64*17;
    #pragma unroll
    for (int k2 = 0; k2 < 4; ++k2) {
        red_d[(4*tt + k2)*17 + cc] = bd[k2];
        red_i[(4*tt + k2)*17 + cc] = bi[k2];
    }
    __syncthreads();
    if (tid < 64) {
        float b = red_d[tid*17]; int ix = red_i[tid*17];
        #pragma unroll
        for (int q = 1; q < 16; ++q) {
            float d = red_d[tid*17 + q]; int i2 = red_i[tid*17 + q];
            if (d < b || (d == b && i2 < ix)) { b = d; ix = i2; }
        }
        int g = tok0 + tid;
        sc[modal*NTOK + g] = ix;
        out_w[OFF_SC + (size_t)modal*NTOK + g] = (float)ix;
    }
}

// ---------------- stable counting sort: per-block hist ----------------
__global__ __launch_bounds__(256) void k_hist(const int* __restrict__ sc,
                                              int* __restrict__ blockHist)
{
    int modal = blockIdx.y, blk = blockIdx.x, tid = threadIdx.x;
    __shared__ int h[512];
    h[tid] = 0; h[tid + 256] = 0;
    __syncthreads();
    atomicAdd(&h[sc[modal*NTOK + blk*256 + tid]], 1);
    __syncthreads();
    int base = (modal*128 + blk) * 512;
    blockHist[base + tid]       = h[tid];
    blockHist[base + tid + 256] = h[tid + 256];
}

// ---------------- per-class block scan + class exclusive scan ----------------
__global__ __launch_bounds__(512) void k_scan(const int* __restrict__ blockHist,
                                              int* __restrict__ blockBase,
                                              int* __restrict__ classBase,
                                              float* __restrict__ out)
{
    int modal = blockIdx.x;
    int c = threadIdx.x;
    int run = 0;
    for (int b = 0; b < 128; ++b) {
        int idx = (modal*128 + b)*512 + c;
        blockBase[idx] = run;
        run += blockHist[idx];
    }
    float* cnt = out + (modal ? OFF_CI : OFF_CT);
    cnt[c] = (float)run;

    __shared__ int s[512];
    s[c] = run;
    __syncthreads();
    int total = run;
    for (int off = 1; off < 512; off <<= 1) {
        int v = 0;
        if (c >= off) v = s[c - off];
        __syncthreads();
        s[c] += v;
        __syncthreads();
    }
    classBase[modal*512 + c] = s[c] - total;   // exclusive prefix
}

// ---------------- stable scatter (in-block O(n^2/2) rank) ----------------
__global__ __launch_bounds__(256) void k_scatter(const int* __restrict__ sc,
                                                 const int* __restrict__ blockBase,
                                                 const int* __restrict__ classBase,
                                                 float* __restrict__ out)
{
    int modal = blockIdx.y, blk = blockIdx.x, tid = threadIdx.x;
    __shared__ int cls[256];
    int t = blk*256 + tid;
    int c = sc[modal*NTOK + t];
    cls[tid] = c;
    __syncthreads();
    int rank = 0;
    for (int j = 0; j < tid; ++j) rank += (cls[j] == c) ? 1 : 0;
    int pos = classBase[modal*512 + c] + blockBase[(modal*128 + blk)*512 + c] + rank;
    float* oo = out + (modal ? OFF_OI : OFF_OT);
    oo[pos] = (float)t;
}

extern "C" void kernel_launch(void* const* d_in, const int* in_sizes, int n_in,
                              void* d_out, int out_size, void* d_ws, size_t ws_size,
                              hipStream_t stream)
{
    const float* text_emb  = (const float*)d_in[0];
    const float* image_emb = (const float*)d_in[1];
    const float* W[2][3] = {
        {(const float*)d_in[2], (const float*)d_in[3], (const float*)d_in[4]},
        {(const float*)d_in[5], (const float*)d_in[6], (const float*)d_in[7]}
    };
    const float* cent_raw = (const float*)d_in[8];
    float* out = (float*)d_out;

    int*   sc        = (int*)d_ws;                            // [2][32768]
    int*   blockHist = (int*)((char*)d_ws + 262144);          // [2][128][512]
    int*   blockBase = (int*)((char*)d_ws + 786432);          // [2][128][512]
    int*   classBase = (int*)((char*)d_ws + 1310720);         // [2][512]
    float* c2        = (float*)((char*)d_ws + 1314816);       // [512]
    float* hbuf      = (float*)((char*)d_ws + (size_t)(2u << 20));

    size_t avail = ws_size > (size_t)(2u << 20) ? ws_size - (size_t)(2u << 20) : 0;
    int chunk = 128;
    for (int c = 32768; c >= 128; c >>= 1) {
        if ((size_t)c * 8192 <= avail) { chunk = c; break; }
    }

    k_cent<<<dim3(512), dim3(64), 0, stream>>>(cent_raw, out, c2);
    k_wc  <<<dim3(64),  dim3(256), 0, stream>>>(out);

    for (int m = 0; m < 2; ++m) {
        const float* emb = m ? image_emb : text_emb;
        float* h1 = hbuf;
        float* h2 = hbuf + (size_t)chunk * 1024;
        for (int s0 = 0; s0 < NTOK; s0 += chunk) {
            k_gemm_tanh<<<dim3(8, chunk/128), dim3(256), 0, stream>>>(
                emb + (size_t)s0*1024, W[m][0], h1, chunk, 1024, 1024);
            k_gemm_tanh<<<dim3(8, chunk/128), dim3(256), 0, stream>>>(
                h1, W[m][1], h2, chunk, 1024, 1024);
            k_gemm_tanh<<<dim3(2, chunk/128), dim3(256), 0, stream>>>(
                h2, W[m][2], out + OFF_SE + ((size_t)m*NTOK + s0)*256, chunk, 256, 1024);
        }
    }

    k_assign <<<dim3(512, 2), dim3(256), 0, stream>>>(out, c2, sc, out);
    k_hist   <<<dim3(128, 2), dim3(256), 0, stream>>>(sc, blockHist);
    k_scan   <<<dim3(2),      dim3(512), 0, stream>>>(blockHist, blockBase, classBase, out);
    k_scatter<<<dim3(128, 2), dim3(256), 0, stream>>>(sc, blockBase, classBase, out);
}

// Round 2
// 1611.664 us; speedup vs baseline: 2.4770x; 2.4770x over previous
//
#include <hip/hip_runtime.h>
#include <math.h>

#define NTOK 32768
typedef unsigned short ushort_t;

// d_out offsets (in floats)
#define OFF_CENT 0
#define OFF_SE   131072
#define OFF_WC   16908288
#define OFF_SC   16973824
#define OFF_OT   17039360
#define OFF_CT   17072128
#define OFF_OI   17072640
#define OFF_CI   17105408

typedef __attribute__((ext_vector_type(8))) short short8v;
typedef __attribute__((ext_vector_type(4))) float f32x4;

__device__ __forceinline__ float dot4(float4 a, float4 b){
    return a.x*b.x + a.y*b.y + a.z*b.z + a.w*b.w;
}

// RNE float -> bf16 bits
__device__ __forceinline__ ushort_t f2bf(float x){
    unsigned int u = __float_as_uint(x);
    unsigned int r = (u + 0x7fffu + ((u >> 16) & 1u)) >> 16;
    return (ushort_t)r;
}
__device__ __forceinline__ float bf2f(ushort_t h){
    return __uint_as_float(((unsigned int)h) << 16);
}

__device__ __forceinline__ void gload16(const void* g, void* l){
    __builtin_amdgcn_global_load_lds(
        (const __attribute__((address_space(1))) void*)g,
        (__attribute__((address_space(3))) void*)l,
        16, 0, 0);
}

// ---------------- centroids: tanh + c2 ----------------
__global__ __launch_bounds__(64) void k_cent(const float* __restrict__ raw,
                                             float* __restrict__ out,
                                             float* __restrict__ c2)
{
    int c = blockIdx.x, l = threadIdx.x;
    float4 v = *(const float4*)(raw + (size_t)c*256 + l*4);
    float4 t;
    t.x = tanhf(v.x); t.y = tanhf(v.y); t.z = tanhf(v.z); t.w = tanhf(v.w);
    *(float4*)(out + OFF_CENT + (size_t)c*256 + l*4) = t;
    float s = dot4(t, t);
    #pragma unroll
    for (int off = 32; off > 0; off >>= 1) s += __shfl_down(s, off);
    if (l == 0) c2[c] = s;
}

// ---------------- word_class fill ----------------
__global__ __launch_bounds__(256) void k_wc(float* __restrict__ out)
{
    int g = blockIdx.x*256 + threadIdx.x;
    float v = (g*4 < NTOK) ? 0.f : 1.f;
    float4* p = (float4*)(out + OFF_WC);
    p[g] = make_float4(v, v, v, v);
}

// ---------------- emb split: fp32 -> (hi,lo) bf16 ----------------
__global__ __launch_bounds__(256) void k_esplit(const float* __restrict__ x,
                                                ushort_t* __restrict__ hi,
                                                ushort_t* __restrict__ lo,
                                                long n4)
{
    long g = (long)blockIdx.x*256 + threadIdx.x;
    if (g >= n4) return;
    float4 v = ((const float4*)x)[g];
    ushort_t h0 = f2bf(v.x), h1 = f2bf(v.y), h2 = f2bf(v.z), h3 = f2bf(v.w);
    ushort4 h = make_ushort4(h0, h1, h2, h3);
    ushort4 l = make_ushort4(f2bf(v.x - bf2f(h0)), f2bf(v.y - bf2f(h1)),
                             f2bf(v.z - bf2f(h2)), f2bf(v.w - bf2f(h3)));
    ((ushort4*)hi)[g] = h;
    ((ushort4*)lo)[g] = l;
}

// ---------------- weight transpose + split: W[K][N] f32 -> Wt_hi/lo [N][K] bf16 ----------------
__global__ __launch_bounds__(256) void k_wsplit(const float* __restrict__ W,
                                                ushort_t* __restrict__ Wt_hi,
                                                ushort_t* __restrict__ Wt_lo,
                                                int K, int N)
{
    __shared__ float t[32][33];
    int k0 = blockIdx.y*32, n0 = blockIdx.x*32;
    int tx = threadIdx.x & 31, ty = threadIdx.x >> 5;   // ty: 0..7
    #pragma unroll
    for (int r = 0; r < 4; ++r)
        t[ty + r*8][tx] = W[(size_t)(k0 + ty + r*8)*N + n0 + tx];
    __syncthreads();
    #pragma unroll
    for (int r = 0; r < 4; ++r) {
        int n = ty + r*8;
        float x = t[tx][n];                   // W[k0+tx][n0+n]
        ushort_t h = f2bf(x);
        Wt_hi[(size_t)(n0+n)*K + k0 + tx] = h;
        Wt_lo[(size_t)(n0+n)*K + k0 + tx] = f2bf(x - bf2f(h));
    }
}

// ---------------- split-bf16 MFMA GEMM + tanh ----------------
// C = tanh( (A_hi+A_lo)[M,1024] @ (B_hi+B_lo)[1024,N] ), B given transposed [N][1024].
// 128x128 tile, BK=32, 256 threads (4 waves, 2x2), 16x16x32 bf16 MFMA, 3-term split.
// mode 0: write C as (hi,lo) bf16 pair [M][N]; mode 1: write fp32 to Cf.
__global__ __launch_bounds__(256, 2) void k_gemm_mfma(
    const ushort_t* __restrict__ A_hi, const ushort_t* __restrict__ A_lo,
    const ushort_t* __restrict__ Bt_hi, const ushort_t* __restrict__ Bt_lo,
    ushort_t* __restrict__ C_hi, ushort_t* __restrict__ C_lo,
    float* __restrict__ Cf,
    int N, int mode)
{
    const int K = 1024;
    __shared__ ushort_t lds[16384];   // 32 KiB: A_hi | A_lo | Bt_hi | Bt_lo, each [128][32]

    const int tid  = threadIdx.x;
    const int wave = tid >> 6, lane = tid & 63;
    const int wr = wave >> 1, wc = wave & 1;
    const int m0 = blockIdx.y * 128, n0 = blockIdx.x * 128;

    f32x4 acc[4][4] = {};

    // staging coords (2 rounds per tile per wave; 16B per lane)
    int srow[2], sq[2], slbase[2];
    #pragma unroll
    for (int r = 0; r < 2; ++r) {
        int row = wave*32 + r*16 + (lane >> 2);
        srow[r]   = row;
        sq[r]     = (lane & 3) ^ ((row >> 1) & 3);
        slbase[r] = wave*1024 + r*512 + 0;     // in ushorts within a tile region
    }

    const int fr = lane & 15, fq = lane >> 4;

    for (int kt = 0; kt < K; kt += 32) {
        __syncthreads();   // previous iteration's ds_reads complete
        #pragma unroll
        for (int r = 0; r < 2; ++r) {
            size_t ga = (size_t)(m0 + srow[r]) * K + kt + sq[r]*8;
            size_t gb = (size_t)(n0 + srow[r]) * K + kt + sq[r]*8;
            gload16(A_hi  + ga, lds          + slbase[r]);
            gload16(A_lo  + ga, lds + 4096   + slbase[r]);
            gload16(Bt_hi + gb, lds + 8192   + slbase[r]);
            gload16(Bt_lo + gb, lds + 12288  + slbase[r]);
        }
        __syncthreads();   // staging drained (vmcnt(0) before barrier)

        short8v ah[4], al[4], bh[4], bl[4];
        #pragma unroll
        for (int i = 0; i < 4; ++i) {
            int rowa = wr*64 + i*16 + fr;
            int offa = rowa*32 + ((fq ^ ((rowa >> 1) & 3)) * 8);
            ah[i] = *(const short8v*)(lds + offa);
            al[i] = *(const short8v*)(lds + 4096 + offa);
            int rowb = wc*64 + i*16 + fr;
            int offb = rowb*32 + ((fq ^ ((rowb >> 1) & 3)) * 8);
            bh[i] = *(const short8v*)(lds + 8192 + offb);
            bl[i] = *(const short8v*)(lds + 12288 + offb);
        }
        #pragma unroll
        for (int i = 0; i < 4; ++i)
            #pragma unroll
            for (int j = 0; j < 4; ++j) {
                acc[i][j] = __builtin_amdgcn_mfma_f32_16x16x32_bf16(ah[i], bh[j], acc[i][j], 0, 0, 0);
                acc[i][j] = __builtin_amdgcn_mfma_f32_16x16x32_bf16(ah[i], bl[j], acc[i][j], 0, 0, 0);
                acc[i][j] = __builtin_amdgcn_mfma_f32_16x16x32_bf16(al[i], bh[j], acc[i][j], 0, 0, 0);
            }
    }

    // epilogue: C/D layout col = lane&15, row = (lane>>4)*4 + reg  [m89-verified]
    #pragma unroll
    for (int i = 0; i < 4; ++i)
        #pragma unroll
        for (int j = 0; j < 4; ++j)
            #pragma unroll
            for (int r = 0; r < 4; ++r) {
                int row = m0 + wr*64 + i*16 + fq*4 + r;
                int col = n0 + wc*64 + j*16 + fr;
                float t = tanhf(acc[i][j][r]);
                if (mode == 0) {
                    ushort_t h = f2bf(t);
                    C_hi[(size_t)row*N + col] = h;
                    C_lo[(size_t)row*N + col] = f2bf(t - bf2f(h));
                } else {
                    Cf[(size_t)row*N + col] = t;
                }
            }
}

// ---------------- assignment: argmin_k (c2 + e2 - 2*dot) ----------------
__global__ __launch_bounds__(256) void k_assign(
    const float* __restrict__ out_ro,
    const float* __restrict__ c2,
    int* __restrict__ sc,
    float* __restrict__ out_w)
{
    const int modal = blockIdx.y;
    const int tok0 = blockIdx.x * 64;
    const float* se   = out_ro + OFF_SE + (size_t)modal * NTOK * 256;
    const float* cent = out_ro + OFF_CENT;

    __shared__ float4 se4[64][64];
    __shared__ float4 ct4[64][64];

    const int tid = threadIdx.x;
    const int tt = tid & 15, cc = tid >> 4;

    {
        int rbase = tid >> 6;
        int d4 = tid & 63;
        #pragma unroll
        for (int i = 0; i < 16; ++i) {
            int t = i*4 + rbase;
            float4 v = *(const float4*)(se + (size_t)(tok0 + t)*256 + d4*4);
            se4[t][d4 ^ (t >> 2)] = v;
        }
    }
    __syncthreads();

    float e2r[4];
    #pragma unroll
    for (int k2 = 0; k2 < 4; ++k2) {
        float s = 0.f;
        for (int d4 = 0; d4 < 64; ++d4) {
            float4 v = se4[4*tt + k2][d4 ^ tt];
            s += dot4(v, v);
        }
        e2r[k2] = s;
    }

    float bd[4]; int bi[4];
    #pragma unroll
    for (int k2 = 0; k2 < 4; ++k2) { bd[k2] = 3.4e38f; bi[k2] = 0; }

    for (int ctile = 0; ctile < 8; ++ctile) {
        int c0 = ctile * 64;
        {
            int rbase = tid >> 6;
            int d4 = tid & 63;
            #pragma unroll
            for (int i = 0; i < 16; ++i) {
                int r = i*4 + rbase;
                float4 v = *(const float4*)(cent + (size_t)(c0 + r)*256 + d4*4);
                ct4[r][d4 ^ (r >> 2)] = v;
            }
        }
        __syncthreads();

        float accd[4][4];
        #pragma unroll
        for (int a = 0; a < 4; ++a)
            #pragma unroll
            for (int b = 0; b < 4; ++b) accd[a][b] = 0.f;

        for (int d4 = 0; d4 < 64; ++d4) {
            float4 sv[4], cv[4];
            #pragma unroll
            for (int k2 = 0; k2 < 4; ++k2) sv[k2] = se4[4*tt + k2][d4 ^ tt];
            #pragma unroll
            for (int j = 0; j < 4; ++j)    cv[j]  = ct4[4*cc + j ][d4 ^ cc];
            #pragma unroll
            for (int k2 = 0; k2 < 4; ++k2)
                #pragma unroll
                for (int j = 0; j < 4; ++j)
                    accd[k2][j] += dot4(sv[k2], cv[j]);
        }

        #pragma unroll
        for (int j = 0; j < 4; ++j) {
            int cidx = c0 + 4*cc + j;
            float cj = c2[cidx];
            #pragma unroll
            for (int k2 = 0; k2 < 4; ++k2) {
                float d = cj + e2r[k2] - 2.f * accd[k2][j];
                if (d < bd[k2]) { bd[k2] = d; bi[k2] = cidx; }
            }
        }
        __syncthreads();
    }

    float* red_d = (float*)ct4;
    int*   red_i = (int*)ct4 + 64*17;
    #pragma unroll
    for (int k2 = 0; k2 < 4; ++k2) {
        red_d[(4*tt + k2)*17 + cc] = bd[k2];
        red_i[(4*tt + k2)*17 + cc] = bi[k2];
    }
    __syncthreads();
    if (tid < 64) {
        float b = red_d[tid*17]; int ix = red_i[tid*17];
        #pragma unroll
        for (int q = 1; q < 16; ++q) {
            float d = red_d[tid*17 + q]; int i2 = red_i[tid*17 + q];
            if (d < b || (d == b && i2 < ix)) { b = d; ix = i2; }
        }
        int g = tok0 + tid;
        sc[modal*NTOK + g] = ix;
        out_w[OFF_SC + (size_t)modal*NTOK + g] = (float)ix;
    }
}

// ---------------- stable counting sort ----------------
__global__ __launch_bounds__(256) void k_hist(const int* __restrict__ sc,
                                              int* __restrict__ blockHist)
{
    int modal = blockIdx.y, blk = blockIdx.x, tid = threadIdx.x;
    __shared__ int h[512];
    h[tid] = 0; h[tid + 256] = 0;
    __syncthreads();
    atomicAdd(&h[sc[modal*NTOK + blk*256 + tid]], 1);
    __syncthreads();
    int base = (modal*128 + blk) * 512;
    blockHist[base + tid]       = h[tid];
    blockHist[base + tid + 256] = h[tid + 256];
}

__global__ __launch_bounds__(512) void k_scan(const int* __restrict__ blockHist,
                                              int* __restrict__ blockBase,
                                              int* __restrict__ classBase,
                                              float* __restrict__ out)
{
    int modal = blockIdx.x;
    int c = threadIdx.x;
    int run = 0;
    for (int b = 0; b < 128; ++b) {
        int idx = (modal*128 + b)*512 + c;
        blockBase[idx] = run;
        run += blockHist[idx];
    }
    float* cnt = out + (modal ? OFF_CI : OFF_CT);
    cnt[c] = (float)run;

    __shared__ int s[512];
    s[c] = run;
    __syncthreads();
    int total = run;
    for (int off = 1; off < 512; off <<= 1) {
        int v = 0;
        if (c >= off) v = s[c - off];
        __syncthreads();
        s[c] += v;
        __syncthreads();
    }
    classBase[modal*512 + c] = s[c] - total;
}

__global__ __launch_bounds__(256) void k_scatter(const int* __restrict__ sc,
                                                 const int* __restrict__ blockBase,
                                                 const int* __restrict__ classBase,
                                                 float* __restrict__ out)
{
    int modal = blockIdx.y, blk = blockIdx.x, tid = threadIdx.x;
    __shared__ int cls[256];
    int t = blk*256 + tid;
    int c = sc[modal*NTOK + t];
    cls[tid] = c;
    __syncthreads();
    int rank = 0;
    for (int j = 0; j < tid; ++j) rank += (cls[j] == c) ? 1 : 0;
    int pos = classBase[modal*512 + c] + blockBase[(modal*128 + blk)*512 + c] + rank;
    float* oo = out + (modal ? OFF_OI : OFF_OT);
    oo[pos] = (float)t;
}

extern "C" void kernel_launch(void* const* d_in, const int* in_sizes, int n_in,
                              void* d_out, int out_size, void* d_ws, size_t ws_size,
                              hipStream_t stream)
{
    const float* text_emb  = (const float*)d_in[0];
    const float* image_emb = (const float*)d_in[1];
    const float* W[2][3] = {
        {(const float*)d_in[2], (const float*)d_in[3], (const float*)d_in[4]},
        {(const float*)d_in[5], (const float*)d_in[6], (const float*)d_in[7]}
    };
    const float* cent_raw = (const float*)d_in[8];
    float* out = (float*)d_out;
    char* w = (char*)d_ws;

    int*   sc        = (int*)w;                      // 256 KB
    int*   blockHist = (int*)(w + 0x40000);          // 512 KB
    int*   blockBase = (int*)(w + 0xC0000);          // 512 KB
    int*   classBase = (int*)(w + 0x140000);         // 4 KB
    float* c2        = (float*)(w + 0x141000);       // 2 KB

    // weight region: per modal {W1t_hi,W1t_lo,W2t_hi,W2t_lo (1M each), W3t_hi,W3t_lo (256K each)} ushorts
    ushort_t* wreg = (ushort_t*)(w + 0x200000);
    const size_t WM = 4*1048576 + 2*262144;          // ushorts per modal = 4.5M
    // activation region
    ushort_t* act = (ushort_t*)(w + 0x200000 + 2*WM*sizeof(ushort_t));   // = 20 MB offset
    size_t actoff = 0x200000 + 2*WM*sizeof(ushort_t);

    // adaptive M-chunk: need actoff + Mc*1024*2B*4
    int Mc = 2048;
    for (int c = NTOK; c >= 2048; c >>= 1) {
        if (actoff + (size_t)c*8192 <= ws_size) { Mc = c; break; }
    }

    k_cent<<<dim3(512), dim3(64), 0, stream>>>(cent_raw, out, c2);
    k_wc  <<<dim3(64),  dim3(256), 0, stream>>>(out);

    for (int m = 0; m < 2; ++m) {
        const float* emb = m ? image_emb : text_emb;
        ushort_t* w1h = wreg + (size_t)m*WM;
        ushort_t* w1l = w1h + 1048576;
        ushort_t* w2h = w1l + 1048576;
        ushort_t* w2l = w2h + 1048576;
        ushort_t* w3h = w2l + 1048576;
        ushort_t* w3l = w3h + 262144;

        k_wsplit<<<dim3(32, 32), dim3(256), 0, stream>>>(W[m][0], w1h, w1l, 1024, 1024);
        k_wsplit<<<dim3(32, 32), dim3(256), 0, stream>>>(W[m][1], w2h, w2l, 1024, 1024);
        k_wsplit<<<dim3(8,  32), dim3(256), 0, stream>>>(W[m][2], w3h, w3l, 1024, 256);

        ushort_t* Ah = act;
        ushort_t* Al = Ah + (size_t)Mc*1024;
        ushort_t* Hh = Al + (size_t)Mc*1024;
        ushort_t* Hl = Hh + (size_t)Mc*1024;

        for (int s0 = 0; s0 < NTOK; s0 += Mc) {
            long n4 = (long)Mc*1024/4;
            k_esplit<<<dim3((unsigned)((n4 + 255)/256)), dim3(256), 0, stream>>>(
                emb + (size_t)s0*1024, Ah, Al, n4);
            k_gemm_mfma<<<dim3(8, Mc/128), dim3(256), 0, stream>>>(
                Ah, Al, w1h, w1l, Hh, Hl, nullptr, 1024, 0);
            k_gemm_mfma<<<dim3(8, Mc/128), dim3(256), 0, stream>>>(
                Hh, Hl, w2h, w2l, Ah, Al, nullptr, 1024, 0);
            k_gemm_mfma<<<dim3(2, Mc/128), dim3(256), 0, stream>>>(
                Ah, Al, w3h, w3l, nullptr, nullptr,
                out + OFF_SE + ((size_t)m*NTOK + s0)*256, 256, 1);
        }
    }

    k_assign <<<dim3(512, 2), dim3(256), 0, stream>>>(out, c2, sc, out);
    k_hist   <<<dim3(128, 2), dim3(256), 0, stream>>>(sc, blockHist);
    k_scan   <<<dim3(2),      dim3(512), 0, stream>>>(blockHist, blockBase, classBase, out);
    k_scatter<<<dim3(128, 2), dim3(256), 0, stream>>>(sc, blockBase, classBase, out);
}

// Round 3
// 1298.120 us; speedup vs baseline: 3.0753x; 1.2415x over previous
//
#include <hip/hip_runtime.h>
#include <math.h>

#define NTOK 32768
typedef unsigned short ushort_t;

// d_out offsets (in floats)
#define OFF_CENT 0
#define OFF_SE   131072
#define OFF_WC   16908288
#define OFF_SC   16973824
#define OFF_OT   17039360
#define OFF_CT   17072128
#define OFF_OI   17072640
#define OFF_CI   17105408

typedef __attribute__((ext_vector_type(8))) short short8v;
typedef __attribute__((ext_vector_type(4))) float f32x4;

__device__ __forceinline__ float dot4(float4 a, float4 b){
    return a.x*b.x + a.y*b.y + a.z*b.z + a.w*b.w;
}

// RNE float -> bf16 bits
__device__ __forceinline__ ushort_t f2bf(float x){
    unsigned int u = __float_as_uint(x);
    unsigned int r = (u + 0x7fffu + ((u >> 16) & 1u)) >> 16;
    return (ushort_t)r;
}
__device__ __forceinline__ float bf2f(ushort_t h){
    return __uint_as_float(((unsigned int)h) << 16);
}

__device__ __forceinline__ void gload16(const void* g, void* l){
    __builtin_amdgcn_global_load_lds(
        (const __attribute__((address_space(1))) void*)g,
        (__attribute__((address_space(3))) void*)l,
        16, 0, 0);
}

// ---------------- centroids: tanh + c2 + hi/lo split ----------------
__global__ __launch_bounds__(64) void k_cent(const float* __restrict__ raw,
                                             float* __restrict__ out,
                                             float* __restrict__ c2,
                                             ushort_t* __restrict__ ch,
                                             ushort_t* __restrict__ cl)
{
    int c = blockIdx.x, l = threadIdx.x;
    float4 v = *(const float4*)(raw + (size_t)c*256 + l*4);
    float4 t;
    t.x = tanhf(v.x); t.y = tanhf(v.y); t.z = tanhf(v.z); t.w = tanhf(v.w);
    *(float4*)(out + OFF_CENT + (size_t)c*256 + l*4) = t;
    ushort4 h = make_ushort4(f2bf(t.x), f2bf(t.y), f2bf(t.z), f2bf(t.w));
    ushort4 lo = make_ushort4(f2bf(t.x - bf2f(h.x)), f2bf(t.y - bf2f(h.y)),
                              f2bf(t.z - bf2f(h.z)), f2bf(t.w - bf2f(h.w)));
    *(ushort4*)(ch + (size_t)c*256 + l*4) = h;
    *(ushort4*)(cl + (size_t)c*256 + l*4) = lo;
    float s = dot4(t, t);
    #pragma unroll
    for (int off = 32; off > 0; off >>= 1) s += __shfl_down(s, off);
    if (l == 0) c2[c] = s;
}

// ---------------- word_class fill ----------------
__global__ __launch_bounds__(256) void k_wc(float* __restrict__ out)
{
    int g = blockIdx.x*256 + threadIdx.x;
    float v = (g*4 < NTOK) ? 0.f : 1.f;
    float4* p = (float4*)(out + OFF_WC);
    p[g] = make_float4(v, v, v, v);
}

// ---------------- emb split: fp32 -> (hi,lo) bf16 ----------------
__global__ __launch_bounds__(256) void k_esplit(const float* __restrict__ x,
                                                ushort_t* __restrict__ hi,
                                                ushort_t* __restrict__ lo,
                                                long n4)
{
    long g = (long)blockIdx.x*256 + threadIdx.x;
    if (g >= n4) return;
    float4 v = ((const float4*)x)[g];
    ushort_t h0 = f2bf(v.x), h1 = f2bf(v.y), h2 = f2bf(v.z), h3 = f2bf(v.w);
    ushort4 h = make_ushort4(h0, h1, h2, h3);
    ushort4 l = make_ushort4(f2bf(v.x - bf2f(h0)), f2bf(v.y - bf2f(h1)),
                             f2bf(v.z - bf2f(h2)), f2bf(v.w - bf2f(h3)));
    ((ushort4*)hi)[g] = h;
    ((ushort4*)lo)[g] = l;
}

// ---------------- weight transpose + split ----------------
__global__ __launch_bounds__(256) void k_wsplit(const float* __restrict__ W,
                                                ushort_t* __restrict__ Wt_hi,
                                                ushort_t* __restrict__ Wt_lo,
                                                int K, int N)
{
    __shared__ float t[32][33];
    int k0 = blockIdx.y*32, n0 = blockIdx.x*32;
    int tx = threadIdx.x & 31, ty = threadIdx.x >> 5;
    #pragma unroll
    for (int r = 0; r < 4; ++r)
        t[ty + r*8][tx] = W[(size_t)(k0 + ty + r*8)*N + n0 + tx];
    __syncthreads();
    #pragma unroll
    for (int r = 0; r < 4; ++r) {
        int n = ty + r*8;
        float x = t[tx][n];
        ushort_t h = f2bf(x);
        Wt_hi[(size_t)(n0+n)*K + k0 + tx] = h;
        Wt_lo[(size_t)(n0+n)*K + k0 + tx] = f2bf(x - bf2f(h));
    }
}

// ---------------- split-bf16 MFMA GEMM + tanh ----------------
// C = tanh( (A_hi+A_lo)[M,1024] @ (B_hi+B_lo)[1024,N] ), B given transposed [N][1024].
// Writes hi/lo bf16 pair if C_hi != nullptr; writes fp32 if Cf != nullptr.
__global__ __launch_bounds__(256, 2) void k_gemm_mfma(
    const ushort_t* __restrict__ A_hi, const ushort_t* __restrict__ A_lo,
    const ushort_t* __restrict__ Bt_hi, const ushort_t* __restrict__ Bt_lo,
    ushort_t* __restrict__ C_hi, ushort_t* __restrict__ C_lo,
    float* __restrict__ Cf,
    int N)
{
    const int K = 1024;
    __shared__ ushort_t lds[16384];   // 32 KiB: A_hi | A_lo | Bt_hi | Bt_lo, each [128][32]

    const int tid  = threadIdx.x;
    const int wave = tid >> 6, lane = tid & 63;
    const int wr = wave >> 1, wc = wave & 1;
    const int m0 = blockIdx.y * 128, n0 = blockIdx.x * 128;

    f32x4 acc[4][4] = {};

    int srow[2], sq[2], slbase[2];
    #pragma unroll
    for (int r = 0; r < 2; ++r) {
        int row = wave*32 + r*16 + (lane >> 2);
        srow[r]   = row;
        sq[r]     = (lane & 3) ^ ((row >> 1) & 3);
        slbase[r] = wave*1024 + r*512;
    }

    const int fr = lane & 15, fq = lane >> 4;

    for (int kt = 0; kt < K; kt += 32) {
        __syncthreads();
        #pragma unroll
        for (int r = 0; r < 2; ++r) {
            size_t ga = (size_t)(m0 + srow[r]) * K + kt + sq[r]*8;
            size_t gb = (size_t)(n0 + srow[r]) * K + kt + sq[r]*8;
            gload16(A_hi  + ga, lds          + slbase[r]);
            gload16(A_lo  + ga, lds + 4096   + slbase[r]);
            gload16(Bt_hi + gb, lds + 8192   + slbase[r]);
            gload16(Bt_lo + gb, lds + 12288  + slbase[r]);
        }
        __syncthreads();

        short8v ah[4], al[4], bh[4], bl[4];
        #pragma unroll
        for (int i = 0; i < 4; ++i) {
            int rowa = wr*64 + i*16 + fr;
            int offa = rowa*32 + ((fq ^ ((rowa >> 1) & 3)) * 8);
            ah[i] = *(const short8v*)(lds + offa);
            al[i] = *(const short8v*)(lds + 4096 + offa);
            int rowb = wc*64 + i*16 + fr;
            int offb = rowb*32 + ((fq ^ ((rowb >> 1) & 3)) * 8);
            bh[i] = *(const short8v*)(lds + 8192 + offb);
            bl[i] = *(const short8v*)(lds + 12288 + offb);
        }
        #pragma unroll
        for (int i = 0; i < 4; ++i)
            #pragma unroll
            for (int j = 0; j < 4; ++j) {
                acc[i][j] = __builtin_amdgcn_mfma_f32_16x16x32_bf16(ah[i], bh[j], acc[i][j], 0, 0, 0);
                acc[i][j] = __builtin_amdgcn_mfma_f32_16x16x32_bf16(ah[i], bl[j], acc[i][j], 0, 0, 0);
                acc[i][j] = __builtin_amdgcn_mfma_f32_16x16x32_bf16(al[i], bh[j], acc[i][j], 0, 0, 0);
            }
    }

    // epilogue: C/D layout col = lane&15, row = (lane>>4)*4 + reg  [m89-verified]
    #pragma unroll
    for (int i = 0; i < 4; ++i)
        #pragma unroll
        for (int j = 0; j < 4; ++j)
            #pragma unroll
            for (int r = 0; r < 4; ++r) {
                int row = m0 + wr*64 + i*16 + fq*4 + r;
                int col = n0 + wc*64 + j*16 + fr;
                float t = tanhf(acc[i][j][r]);
                size_t idx = (size_t)row*N + col;
                if (Cf) Cf[idx] = t;
                if (C_hi) {
                    ushort_t h = f2bf(t);
                    C_hi[idx] = h;
                    C_lo[idx] = f2bf(t - bf2f(h));
                }
            }
}

// ---------------- MFMA assignment: argmin_c (c2[c] - 2 * se.cent) ----------------
// block: 128 tokens x all 512 centroids (4 j-tiles of 128), K=256, 4 waves (2x2).
__global__ __launch_bounds__(256) void k_assign_mfma(
    const ushort_t* __restrict__ SEh, const ushort_t* __restrict__ SEl,
    const ushort_t* __restrict__ ch, const ushort_t* __restrict__ cl,
    const float* __restrict__ c2,
    int* __restrict__ sc, float* __restrict__ out_w)
{
    __shared__ ushort_t lds[16384];   // seH | seL | ctH | ctL, each [128][32]
    __shared__ float c2s[512];
    __shared__ float redD[128][2];
    __shared__ int   redI[128][2];

    const int modal = blockIdx.y;
    const int t0 = blockIdx.x * 128;
    const int tid  = threadIdx.x;
    const int wave = tid >> 6, lane = tid & 63;
    const int wr = wave >> 1, wc = wave & 1;
    const int fr = lane & 15, fq = lane >> 4;

    const ushort_t* seh = SEh + (size_t)modal * NTOK * 256;
    const ushort_t* sel = SEl + (size_t)modal * NTOK * 256;

    c2s[tid] = c2[tid];
    c2s[tid + 256] = c2[tid + 256];

    int srow[2], sq[2], slbase[2];
    #pragma unroll
    for (int r = 0; r < 2; ++r) {
        int row = wave*32 + r*16 + (lane >> 2);
        srow[r]   = row;
        sq[r]     = (lane & 3) ^ ((row >> 1) & 3);
        slbase[r] = wave*1024 + r*512;
    }

    float bd[16]; int bi[16];
    #pragma unroll
    for (int s = 0; s < 16; ++s) { bd[s] = 3.4e38f; bi[s] = 0; }

    for (int j = 0; j < 4; ++j) {
        f32x4 acc[4][4] = {};
        for (int kt = 0; kt < 256; kt += 32) {
            __syncthreads();
            #pragma unroll
            for (int r = 0; r < 2; ++r) {
                size_t ga = (size_t)(t0 + srow[r]) * 256 + kt + sq[r]*8;
                size_t gc = (size_t)(j*128 + srow[r]) * 256 + kt + sq[r]*8;
                gload16(seh + ga, lds          + slbase[r]);
                gload16(sel + ga, lds + 4096   + slbase[r]);
                gload16(ch  + gc, lds + 8192   + slbase[r]);
                gload16(cl  + gc, lds + 12288  + slbase[r]);
            }
            __syncthreads();

            short8v ah[4], al[4], bh[4], bl[4];
            #pragma unroll
            for (int i = 0; i < 4; ++i) {
                int rowa = wr*64 + i*16 + fr;
                int offa = rowa*32 + ((fq ^ ((rowa >> 1) & 3)) * 8);
                ah[i] = *(const short8v*)(lds + offa);
                al[i] = *(const short8v*)(lds + 4096 + offa);
                int rowb = wc*64 + i*16 + fr;
                int offb = rowb*32 + ((fq ^ ((rowb >> 1) & 3)) * 8);
                bh[i] = *(const short8v*)(lds + 8192 + offb);
                bl[i] = *(const short8v*)(lds + 12288 + offb);
            }
            #pragma unroll
            for (int i = 0; i < 4; ++i)
                #pragma unroll
                for (int jj = 0; jj < 4; ++jj) {
                    acc[i][jj] = __builtin_amdgcn_mfma_f32_16x16x32_bf16(ah[i], bh[jj], acc[i][jj], 0, 0, 0);
                    acc[i][jj] = __builtin_amdgcn_mfma_f32_16x16x32_bf16(ah[i], bl[jj], acc[i][jj], 0, 0, 0);
                    acc[i][jj] = __builtin_amdgcn_mfma_f32_16x16x32_bf16(al[i], bh[jj], acc[i][jj], 0, 0, 0);
                }
        }
        // partial argmin over this j-tile (cols ascend with (j, jj) per lane)
        #pragma unroll
        for (int i = 0; i < 4; ++i)
            #pragma unroll
            for (int jj = 0; jj < 4; ++jj) {
                int col = j*128 + wc*64 + jj*16 + fr;
                float cc = c2s[col];
                #pragma unroll
                for (int r = 0; r < 4; ++r) {
                    float d = cc - 2.f * acc[i][jj][r];
                    int s = i*4 + r;
                    if (d < bd[s]) { bd[s] = d; bi[s] = col; }
                }
            }
    }

    // reduce over the 16 lanes (fr) of each fq group; tie -> lower index
    #pragma unroll
    for (int s = 0; s < 16; ++s) {
        #pragma unroll
        for (int off = 1; off < 16; off <<= 1) {
            float od = __shfl_xor(bd[s], off);
            int   oi = __shfl_xor(bi[s], off);
            if (od < bd[s] || (od == bd[s] && oi < bi[s])) { bd[s] = od; bi[s] = oi; }
        }
    }
    if (fr == 0) {
        #pragma unroll
        for (int i = 0; i < 4; ++i)
            #pragma unroll
            for (int r = 0; r < 4; ++r) {
                int tl = wr*64 + i*16 + fq*4 + r;
                redD[tl][wc] = bd[i*4 + r];
                redI[tl][wc] = bi[i*4 + r];
            }
    }
    __syncthreads();
    if (tid < 128) {
        float d0 = redD[tid][0], d1 = redD[tid][1];
        int   i0 = redI[tid][0], i1 = redI[tid][1];
        if (d1 < d0 || (d1 == d0 && i1 < i0)) { d0 = d1; i0 = i1; }
        int g = t0 + tid;
        sc[modal*NTOK + g] = i0;
        out_w[OFF_SC + (size_t)modal*NTOK + g] = (float)i0;
    }
}

// ---------------- fp32 fallback assignment (round-2 proven) ----------------
__global__ __launch_bounds__(256) void k_assign(
    const float* __restrict__ out_ro,
    const float* __restrict__ c2,
    int* __restrict__ sc,
    float* __restrict__ out_w)
{
    const int modal = blockIdx.y;
    const int tok0 = blockIdx.x * 64;
    const float* se   = out_ro + OFF_SE + (size_t)modal * NTOK * 256;
    const float* cent = out_ro + OFF_CENT;

    __shared__ float4 se4[64][64];
    __shared__ float4 ct4[64][64];

    const int tid = threadIdx.x;
    const int tt = tid & 15, cc = tid >> 4;

    {
        int rbase = tid >> 6;
        int d4 = tid & 63;
        #pragma unroll
        for (int i = 0; i < 16; ++i) {
            int t = i*4 + rbase;
            float4 v = *(const float4*)(se + (size_t)(tok0 + t)*256 + d4*4);
            se4[t][d4 ^ (t >> 2)] = v;
        }
    }
    __syncthreads();

    float e2r[4];
    #pragma unroll
    for (int k2 = 0; k2 < 4; ++k2) {
        float s = 0.f;
        for (int d4 = 0; d4 < 64; ++d4) {
            float4 v = se4[4*tt + k2][d4 ^ tt];
            s += dot4(v, v);
        }
        e2r[k2] = s;
    }

    float bd[4]; int bi[4];
    #pragma unroll
    for (int k2 = 0; k2 < 4; ++k2) { bd[k2] = 3.4e38f; bi[k2] = 0; }

    for (int ctile = 0; ctile < 8; ++ctile) {
        int c0 = ctile * 64;
        {
            int rbase = tid >> 6;
            int d4 = tid & 63;
            #pragma unroll
            for (int i = 0; i < 16; ++i) {
                int r = i*4 + rbase;
                float4 v = *(const float4*)(cent + (size_t)(c0 + r)*256 + d4*4);
                ct4[r][d4 ^ (r >> 2)] = v;
            }
        }
        __syncthreads();

        float accd[4][4];
        #pragma unroll
        for (int a = 0; a < 4; ++a)
            #pragma unroll
            for (int b = 0; b < 4; ++b) accd[a][b] = 0.f;

        for (int d4 = 0; d4 < 64; ++d4) {
            float4 sv[4], cv[4];
            #pragma unroll
            for (int k2 = 0; k2 < 4; ++k2) sv[k2] = se4[4*tt + k2][d4 ^ tt];
            #pragma unroll
            for (int jx = 0; jx < 4; ++jx) cv[jx] = ct4[4*cc + jx][d4 ^ cc];
            #pragma unroll
            for (int k2 = 0; k2 < 4; ++k2)
                #pragma unroll
                for (int jx = 0; jx < 4; ++jx)
                    accd[k2][jx] += dot4(sv[k2], cv[jx]);
        }

        #pragma unroll
        for (int jx = 0; jx < 4; ++jx) {
            int cidx = c0 + 4*cc + jx;
            float cj = c2[cidx];
            #pragma unroll
            for (int k2 = 0; k2 < 4; ++k2) {
                float d = cj + e2r[k2] - 2.f * accd[k2][jx];
                if (d < bd[k2]) { bd[k2] = d; bi[k2] = cidx; }
            }
        }
        __syncthreads();
    }

    float* red_d = (float*)ct4;
    int*   red_i = (int*)ct4 + 64*17;
    #pragma unroll
    for (int k2 = 0; k2 < 4; ++k2) {
        red_d[(4*tt + k2)*17 + cc] = bd[k2];
        red_i[(4*tt + k2)*17 + cc] = bi[k2];
    }
    __syncthreads();
    if (tid < 64) {
        float b = red_d[tid*17]; int ix = red_i[tid*17];
        #pragma unroll
        for (int q = 1; q < 16; ++q) {
            float d = red_d[tid*17 + q]; int i2 = red_i[tid*17 + q];
            if (d < b || (d == b && i2 < ix)) { b = d; ix = i2; }
        }
        int g = tok0 + tid;
        sc[modal*NTOK + g] = ix;
        out_w[OFF_SC + (size_t)modal*NTOK + g] = (float)ix;
    }
}

// ---------------- stable counting sort ----------------
__global__ __launch_bounds__(256) void k_hist(const int* __restrict__ sc,
                                              int* __restrict__ blockHist)
{
    int modal = blockIdx.y, blk = blockIdx.x, tid = threadIdx.x;
    __shared__ int h[512];
    h[tid] = 0; h[tid + 256] = 0;
    __syncthreads();
    atomicAdd(&h[sc[modal*NTOK + blk*256 + tid]], 1);
    __syncthreads();
    int base = (modal*128 + blk) * 512;
    blockHist[base + tid]       = h[tid];
    blockHist[base + tid + 256] = h[tid + 256];
}

__global__ __launch_bounds__(512) void k_scan(const int* __restrict__ blockHist,
                                              int* __restrict__ blockBase,
                                              int* __restrict__ classBase,
                                              float* __restrict__ out)
{
    int modal = blockIdx.x;
    int c = threadIdx.x;
    int run = 0;
    for (int b = 0; b < 128; ++b) {
        int idx = (modal*128 + b)*512 + c;
        blockBase[idx] = run;
        run += blockHist[idx];
    }
    float* cnt = out + (modal ? OFF_CI : OFF_CT);
    cnt[c] = (float)run;

    __shared__ int s[512];
    s[c] = run;
    __syncthreads();
    int total = run;
    for (int off = 1; off < 512; off <<= 1) {
        int v = 0;
        if (c >= off) v = s[c - off];
        __syncthreads();
        s[c] += v;
        __syncthreads();
    }
    classBase[modal*512 + c] = s[c] - total;
}

__global__ __launch_bounds__(256) void k_scatter(const int* __restrict__ sc,
                                                 const int* __restrict__ blockBase,
                                                 const int* __restrict__ classBase,
                                                 float* __restrict__ out)
{
    int modal = blockIdx.y, blk = blockIdx.x, tid = threadIdx.x;
    __shared__ int cls[256];
    int t = blk*256 + tid;
    int c = sc[modal*NTOK + t];
    cls[tid] = c;
    __syncthreads();
    int rank = 0;
    for (int j = 0; j < tid; ++j) rank += (cls[j] == c) ? 1 : 0;
    int pos = classBase[modal*512 + c] + blockBase[(modal*128 + blk)*512 + c] + rank;
    float* oo = out + (modal ? OFF_OI : OFF_OT);
    oo[pos] = (float)t;
}

extern "C" void kernel_launch(void* const* d_in, const int* in_sizes, int n_in,
                              void* d_out, int out_size, void* d_ws, size_t ws_size,
                              hipStream_t stream)
{
    const float* text_emb  = (const float*)d_in[0];
    const float* image_emb = (const float*)d_in[1];
    const float* W[2][3] = {
        {(const float*)d_in[2], (const float*)d_in[3], (const float*)d_in[4]},
        {(const float*)d_in[5], (const float*)d_in[6], (const float*)d_in[7]}
    };
    const float* cent_raw = (const float*)d_in[8];
    float* out = (float*)d_out;
    char* w = (char*)d_ws;

    int*   sc        = (int*)w;                      // 256 KB
    int*   blockHist = (int*)(w + 0x40000);          // 512 KB
    int*   blockBase = (int*)(w + 0xC0000);          // 512 KB
    int*   classBase = (int*)(w + 0x140000);         // 4 KB
    float* c2        = (float*)(w + 0x141000);       // 2 KB
    ushort_t* cent_h = (ushort_t*)(w + 0x142000);    // 256 KB
    ushort_t* cent_l = (ushort_t*)(w + 0x182000);    // 256 KB

    // weights: per modal {W1t,W2t hi/lo 1M shorts each, W3t hi/lo 256K shorts}
    ushort_t* wreg = (ushort_t*)(w + 0x200000);
    const size_t WM = 4*1048576 + 2*262144;          // 4.5M ushorts/modal; 18MB total -> ends 0x1400000

    // se hi/lo: [2][NTOK][256] each (32MB each)
    ushort_t* SEh = (ushort_t*)(w + 0x1400000);
    ushort_t* SEl = (ushort_t*)(w + 0x3400000);

    // pick activation layout: prefer MFMA-assign layout (act at 84MB)
    bool mfmaAssign = true;
    size_t actoff = 0x5400000;
    int Mc = 0;
    for (int c = NTOK; c >= 128; c >>= 1)
        if (actoff + (size_t)c*8192 <= ws_size) { Mc = c; break; }
    if (Mc == 0) {
        mfmaAssign = false;
        actoff = 0x1400000;
        for (int c = NTOK; c >= 128; c >>= 1)
            if (actoff + (size_t)c*8192 <= ws_size) { Mc = c; break; }
        if (Mc == 0) Mc = 128;
    }
    ushort_t* act = (ushort_t*)(w + actoff);

    k_cent<<<dim3(512), dim3(64), 0, stream>>>(cent_raw, out, c2, cent_h, cent_l);
    k_wc  <<<dim3(64),  dim3(256), 0, stream>>>(out);

    for (int m = 0; m < 2; ++m) {
        const float* emb = m ? image_emb : text_emb;
        ushort_t* w1h = wreg + (size_t)m*WM;
        ushort_t* w1l = w1h + 1048576;
        ushort_t* w2h = w1l + 1048576;
        ushort_t* w2l = w2h + 1048576;
        ushort_t* w3h = w2l + 1048576;
        ushort_t* w3l = w3h + 262144;

        k_wsplit<<<dim3(32, 32), dim3(256), 0, stream>>>(W[m][0], w1h, w1l, 1024, 1024);
        k_wsplit<<<dim3(32, 32), dim3(256), 0, stream>>>(W[m][1], w2h, w2l, 1024, 1024);
        k_wsplit<<<dim3(8,  32), dim3(256), 0, stream>>>(W[m][2], w3h, w3l, 1024, 256);

        ushort_t* Ah = act;
        ushort_t* Al = Ah + (size_t)Mc*1024;
        ushort_t* Hh = Al + (size_t)Mc*1024;
        ushort_t* Hl = Hh + (size_t)Mc*1024;

        for (int s0 = 0; s0 < NTOK; s0 += Mc) {
            long n4 = (long)Mc*1024/4;
            k_esplit<<<dim3((unsigned)((n4 + 255)/256)), dim3(256), 0, stream>>>(
                emb + (size_t)s0*1024, Ah, Al, n4);
            k_gemm_mfma<<<dim3(8, Mc/128), dim3(256), 0, stream>>>(
                Ah, Al, w1h, w1l, Hh, Hl, nullptr, 1024);
            k_gemm_mfma<<<dim3(8, Mc/128), dim3(256), 0, stream>>>(
                Hh, Hl, w2h, w2l, Ah, Al, nullptr, 1024);
            ushort_t* seh_ptr = mfmaAssign ? SEh + ((size_t)m*NTOK + s0)*256 : nullptr;
            ushort_t* sel_ptr = mfmaAssign ? SEl + ((size_t)m*NTOK + s0)*256 : nullptr;
            k_gemm_mfma<<<dim3(2, Mc/128), dim3(256), 0, stream>>>(
                Ah, Al, w3h, w3l, seh_ptr, sel_ptr,
                out + OFF_SE + ((size_t)m*NTOK + s0)*256, 256);
        }
    }

    if (mfmaAssign) {
        k_assign_mfma<<<dim3(256, 2), dim3(256), 0, stream>>>(
            SEh, SEl, cent_h, cent_l, c2, sc, out);
    } else {
        k_assign<<<dim3(512, 2), dim3(256), 0, stream>>>(out, c2, sc, out);
    }
    k_hist   <<<dim3(128, 2), dim3(256), 0, stream>>>(sc, blockHist);
    k_scan   <<<dim3(2),      dim3(512), 0, stream>>>(blockHist, blockBase, classBase, out);
    k_scatter<<<dim3(128, 2), dim3(256), 0, stream>>>(sc, blockBase, classBase, out);
}

// Round 4
// 1159.743 us; speedup vs baseline: 3.4422x; 1.1193x over previous
//
#include <hip/hip_runtime.h>
#include <math.h>

#define NTOK 32768
typedef unsigned short ushort_t;

// d_out offsets (in floats)
#define OFF_CENT 0
#define OFF_SE   131072
#define OFF_WC   16908288
#define OFF_SC   16973824
#define OFF_OT   17039360
#define OFF_CT   17072128
#define OFF_OI   17072640
#define OFF_CI   17105408

typedef __attribute__((ext_vector_type(8))) short short8v;
typedef __attribute__((ext_vector_type(4))) float f32x4;

__device__ __forceinline__ float dot4(float4 a, float4 b){
    return a.x*b.x + a.y*b.y + a.z*b.z + a.w*b.w;
}

// RNE float -> bf16 bits
__device__ __forceinline__ ushort_t f2bf(float x){
    unsigned int u = __float_as_uint(x);
    unsigned int r = (u + 0x7fffu + ((u >> 16) & 1u)) >> 16;
    return (ushort_t)r;
}
__device__ __forceinline__ float bf2f(ushort_t h){
    return __uint_as_float(((unsigned int)h) << 16);
}

__device__ __forceinline__ void gload16(const void* g, void* l){
    __builtin_amdgcn_global_load_lds(
        (const __attribute__((address_space(1))) void*)g,
        (__attribute__((address_space(3))) void*)l,
        16, 0, 0);
}

// ---------------- centroids: tanh + c2 + hi/lo split ----------------
__global__ __launch_bounds__(64) void k_cent(const float* __restrict__ raw,
                                             float* __restrict__ out,
                                             float* __restrict__ c2,
                                             ushort_t* __restrict__ ch,
                                             ushort_t* __restrict__ cl)
{
    int c = blockIdx.x, l = threadIdx.x;
    float4 v = *(const float4*)(raw + (size_t)c*256 + l*4);
    float4 t;
    t.x = tanhf(v.x); t.y = tanhf(v.y); t.z = tanhf(v.z); t.w = tanhf(v.w);
    *(float4*)(out + OFF_CENT + (size_t)c*256 + l*4) = t;
    ushort4 h = make_ushort4(f2bf(t.x), f2bf(t.y), f2bf(t.z), f2bf(t.w));
    ushort4 lo = make_ushort4(f2bf(t.x - bf2f(h.x)), f2bf(t.y - bf2f(h.y)),
                              f2bf(t.z - bf2f(h.z)), f2bf(t.w - bf2f(h.w)));
    *(ushort4*)(ch + (size_t)c*256 + l*4) = h;
    *(ushort4*)(cl + (size_t)c*256 + l*4) = lo;
    float s = dot4(t, t);
    #pragma unroll
    for (int off = 32; off > 0; off >>= 1) s += __shfl_down(s, off);
    if (l == 0) c2[c] = s;
}

// ---------------- word_class fill ----------------
__global__ __launch_bounds__(256) void k_wc(float* __restrict__ out)
{
    int g = blockIdx.x*256 + threadIdx.x;
    float v = (g*4 < NTOK) ? 0.f : 1.f;
    float4* p = (float4*)(out + OFF_WC);
    p[g] = make_float4(v, v, v, v);
}

// ---------------- emb split: fp32 -> (hi,lo) bf16 ----------------
__global__ __launch_bounds__(256) void k_esplit(const float* __restrict__ x,
                                                ushort_t* __restrict__ hi,
                                                ushort_t* __restrict__ lo,
                                                long n4)
{
    long g = (long)blockIdx.x*256 + threadIdx.x;
    if (g >= n4) return;
    float4 v = ((const float4*)x)[g];
    ushort_t h0 = f2bf(v.x), h1 = f2bf(v.y), h2 = f2bf(v.z), h3 = f2bf(v.w);
    ushort4 h = make_ushort4(h0, h1, h2, h3);
    ushort4 l = make_ushort4(f2bf(v.x - bf2f(h0)), f2bf(v.y - bf2f(h1)),
                             f2bf(v.z - bf2f(h2)), f2bf(v.w - bf2f(h3)));
    ((ushort4*)hi)[g] = h;
    ((ushort4*)lo)[g] = l;
}

// ---------------- weight transpose + split ----------------
__global__ __launch_bounds__(256) void k_wsplit(const float* __restrict__ W,
                                                ushort_t* __restrict__ Wt_hi,
                                                ushort_t* __restrict__ Wt_lo,
                                                int K, int N)
{
    __shared__ float t[32][33];
    int k0 = blockIdx.y*32, n0 = blockIdx.x*32;
    int tx = threadIdx.x & 31, ty = threadIdx.x >> 5;
    #pragma unroll
    for (int r = 0; r < 4; ++r)
        t[ty + r*8][tx] = W[(size_t)(k0 + ty + r*8)*N + n0 + tx];
    __syncthreads();
    #pragma unroll
    for (int r = 0; r < 4; ++r) {
        int n = ty + r*8;
        float x = t[tx][n];
        ushort_t h = f2bf(x);
        Wt_hi[(size_t)(n0+n)*K + k0 + tx] = h;
        Wt_lo[(size_t)(n0+n)*K + k0 + tx] = f2bf(x - bf2f(h));
    }
}

// ================= 256x256 8-wave phase-split split-bf16 GEMM + tanh =================
// C = tanh((A_hi+A_lo)[M,1024] @ (B_hi+B_lo)^T), Bt [N][1024]. K=1024. BK=32.
// 512 threads = 8 waves (2M x 4N), per-wave 128x64 output. LDS 128 KiB (2 bufs).
__global__ __launch_bounds__(512, 2) void k_gemm_mfma256(
    const ushort_t* __restrict__ A_hi, const ushort_t* __restrict__ A_lo,
    const ushort_t* __restrict__ Bt_hi, const ushort_t* __restrict__ Bt_lo,
    ushort_t* __restrict__ C_hi, ushort_t* __restrict__ C_lo,
    int N)
{
    __shared__ ushort_t lds[65536];   // 2 x { Ah[256][32] Al Bh Bl } (each 8192 elems)

    const int tid  = threadIdx.x;
    const int wave = tid >> 6, lane = tid & 63;
    const int wr = wave >> 2, wc = wave & 3;
    const int fr = lane & 15, fq = lane >> 4;

    // T1: bijective XCD swizzle (nwg % 8 == 0 for all uses here)
    int nwg = gridDim.x;
    int id = blockIdx.x;
    if (!(nwg & 7)) { int cpx = nwg >> 3; id = (id & 7)*cpx + (id >> 3); }
    const int nx = N >> 8;
    const int n0 = (id % nx) * 256;
    const int m0 = (id / nx) * 256;

    // staging coords: thread t covers row = r*128 + (t>>2), k-slot t&3 (pre-swizzled source)
    const int srow0 = tid >> 2;
    const int qx = (tid & 3) ^ ((srow0 >> 1) & 3);
    const ushort_t* aptr[4] = {A_hi, A_lo, Bt_hi, Bt_lo};
    const int rbase[4] = {m0, m0, n0, n0};

    // fragment read: XOR slot is lane-only (row components are multiples of 8 in (row>>1))
    const int fbase = fr*32 + ((fq ^ ((fr >> 1) & 3)) * 8);

    f32x4 acc[8][4] = {};

#define STAGE256(KTS, WB) { \
    unsigned wb = (unsigned)(WB) * 32768u; \
    _Pragma("unroll") \
    for (int a_ = 0; a_ < 4; ++a_) { \
        _Pragma("unroll") \
        for (int r_ = 0; r_ < 2; ++r_) \
            gload16(aptr[a_] + (size_t)(rbase[a_] + r_*128 + srow0)*1024 + (KTS) + qx*8, \
                    lds + wb + a_*8192u + (unsigned)(r_*128 + wave*16)*32u); \
    } }

#define LDA256(i, hl) (*(const short8v*)(lds + rb + (hl)*8192u + wr*4096 + (i)*512 + fbase))
#define LDB256(j, hl) (*(const short8v*)(lds + rb + 16384u + (hl)*8192u + wc*2048 + (j)*512 + fbase))

#define MFMA_PAIR(I, AH, AL, J) \
    acc[I][J] = __builtin_amdgcn_mfma_f32_16x16x32_bf16(AH, bh[J], acc[I][J], 0, 0, 0); \
    acc[I][J] = __builtin_amdgcn_mfma_f32_16x16x32_bf16(AH, bl[J], acc[I][J], 0, 0, 0); \
    acc[I][J] = __builtin_amdgcn_mfma_f32_16x16x32_bf16(AL, bh[J], acc[I][J], 0, 0, 0);

    // prologue: stage tile 0 into buf 0
    STAGE256(0, 0);
    asm volatile("s_waitcnt vmcnt(0)" ::: "memory");
    __builtin_amdgcn_s_barrier();

    #pragma unroll 1
    for (int kt = 0; kt < 1024; kt += 32) {
        const int bufR = (kt >> 5) & 1;
        const unsigned rb = (unsigned)bufR * 32768u;
        const bool pf = (kt + 32) < 1024;

        short8v bh[4], bl[4];

        // ---- phase 0: B frags + A(i=0,1); front-load all 8 next-tile stages ----
        {
            #pragma unroll
            for (int j = 0; j < 4; ++j) { bh[j] = LDB256(j, 0); bl[j] = LDB256(j, 1); }
            short8v a0h = LDA256(0,0), a0l = LDA256(0,1);
            short8v a1h = LDA256(1,0), a1l = LDA256(1,1);
            if (pf) STAGE256(kt + 32, bufR ^ 1);
            __builtin_amdgcn_s_barrier();
            asm volatile("s_waitcnt lgkmcnt(0)" ::: "memory");
            __builtin_amdgcn_sched_barrier(0);
            __builtin_amdgcn_s_setprio(1);
            #pragma unroll
            for (int j = 0; j < 4; ++j) { MFMA_PAIR(0, a0h, a0l, j) MFMA_PAIR(1, a1h, a1l, j) }
            __builtin_amdgcn_s_setprio(0);
            __builtin_amdgcn_s_barrier();
        }
        // ---- phases 1..3: A quadrants ----
#define PHASE256(P) { \
            short8v a0h = LDA256(2*(P),0),   a0l = LDA256(2*(P),1); \
            short8v a1h = LDA256(2*(P)+1,0), a1l = LDA256(2*(P)+1,1); \
            __builtin_amdgcn_s_barrier(); \
            asm volatile("s_waitcnt lgkmcnt(0)" ::: "memory"); \
            __builtin_amdgcn_sched_barrier(0); \
            __builtin_amdgcn_s_setprio(1); \
            _Pragma("unroll") \
            for (int j = 0; j < 4; ++j) { MFMA_PAIR(2*(P), a0h, a0l, j) MFMA_PAIR(2*(P)+1, a1h, a1l, j) } \
            __builtin_amdgcn_s_setprio(0); \
            __builtin_amdgcn_s_barrier(); \
        }
        PHASE256(1)
        PHASE256(2)
        PHASE256(3)

        // ---- tile boundary: staged loads (issued in phase 0) must land ----
        asm volatile("s_waitcnt vmcnt(0)" ::: "memory");
        __builtin_amdgcn_s_barrier();
    }

    // epilogue: C/D layout col = lane&15, row = (lane>>4)*4 + reg
    #pragma unroll
    for (int i = 0; i < 8; ++i)
        #pragma unroll
        for (int j = 0; j < 4; ++j)
            #pragma unroll
            for (int r = 0; r < 4; ++r) {
                int row = m0 + wr*128 + i*16 + fq*4 + r;
                int col = n0 + wc*64 + j*16 + fr;
                float t = tanhf(acc[i][j][r]);
                size_t idx = (size_t)row*N + col;
                ushort_t h = f2bf(t);
                C_hi[idx] = h;
                C_lo[idx] = f2bf(t - bf2f(h));
            }
}

// ---------------- 128x128 split-bf16 MFMA GEMM + tanh (layer 3 / fallback) ----------------
__global__ __launch_bounds__(256, 2) void k_gemm_mfma(
    const ushort_t* __restrict__ A_hi, const ushort_t* __restrict__ A_lo,
    const ushort_t* __restrict__ Bt_hi, const ushort_t* __restrict__ Bt_lo,
    ushort_t* __restrict__ C_hi, ushort_t* __restrict__ C_lo,
    float* __restrict__ Cf,
    int N)
{
    const int K = 1024;
    __shared__ ushort_t lds[16384];

    const int tid  = threadIdx.x;
    const int wave = tid >> 6, lane = tid & 63;
    const int wr = wave >> 1, wc = wave & 1;

    int nwg = gridDim.x * gridDim.y;
    int id = blockIdx.y * gridDim.x + blockIdx.x;
    if (!(nwg & 7)) { int cpx = nwg >> 3; id = (id & 7)*cpx + (id >> 3); }
    const int m0 = (id / gridDim.x) * 128, n0 = (id % gridDim.x) * 128;

    f32x4 acc[4][4] = {};

    int srow[2], sq[2], slbase[2];
    #pragma unroll
    for (int r = 0; r < 2; ++r) {
        int row = wave*32 + r*16 + (lane >> 2);
        srow[r]   = row;
        sq[r]     = (lane & 3) ^ ((row >> 1) & 3);
        slbase[r] = wave*1024 + r*512;
    }

    const int fr = lane & 15, fq = lane >> 4;

    for (int kt = 0; kt < K; kt += 32) {
        __syncthreads();
        #pragma unroll
        for (int r = 0; r < 2; ++r) {
            size_t ga = (size_t)(m0 + srow[r]) * K + kt + sq[r]*8;
            size_t gb = (size_t)(n0 + srow[r]) * K + kt + sq[r]*8;
            gload16(A_hi  + ga, lds          + slbase[r]);
            gload16(A_lo  + ga, lds + 4096   + slbase[r]);
            gload16(Bt_hi + gb, lds + 8192   + slbase[r]);
            gload16(Bt_lo + gb, lds + 12288  + slbase[r]);
        }
        __syncthreads();

        short8v ah[4], al[4], bh[4], bl[4];
        #pragma unroll
        for (int i = 0; i < 4; ++i) {
            int rowa = wr*64 + i*16 + fr;
            int offa = rowa*32 + ((fq ^ ((rowa >> 1) & 3)) * 8);
            ah[i] = *(const short8v*)(lds + offa);
            al[i] = *(const short8v*)(lds + 4096 + offa);
            int rowb = wc*64 + i*16 + fr;
            int offb = rowb*32 + ((fq ^ ((rowb >> 1) & 3)) * 8);
            bh[i] = *(const short8v*)(lds + 8192 + offb);
            bl[i] = *(const short8v*)(lds + 12288 + offb);
        }
        #pragma unroll
        for (int i = 0; i < 4; ++i)
            #pragma unroll
            for (int j = 0; j < 4; ++j) {
                acc[i][j] = __builtin_amdgcn_mfma_f32_16x16x32_bf16(ah[i], bh[j], acc[i][j], 0, 0, 0);
                acc[i][j] = __builtin_amdgcn_mfma_f32_16x16x32_bf16(ah[i], bl[j], acc[i][j], 0, 0, 0);
                acc[i][j] = __builtin_amdgcn_mfma_f32_16x16x32_bf16(al[i], bh[j], acc[i][j], 0, 0, 0);
            }
    }

    #pragma unroll
    for (int i = 0; i < 4; ++i)
        #pragma unroll
        for (int j = 0; j < 4; ++j)
            #pragma unroll
            for (int r = 0; r < 4; ++r) {
                int row = m0 + wr*64 + i*16 + fq*4 + r;
                int col = n0 + wc*64 + j*16 + fr;
                float t = tanhf(acc[i][j][r]);
                size_t idx = (size_t)row*N + col;
                if (Cf) Cf[idx] = t;
                if (C_hi) {
                    ushort_t h = f2bf(t);
                    C_hi[idx] = h;
                    C_lo[idx] = f2bf(t - bf2f(h));
                }
            }
}

// ---------------- MFMA assignment: argmin_c (c2[c] - 2 * se.cent) ----------------
__global__ __launch_bounds__(256) void k_assign_mfma(
    const ushort_t* __restrict__ SEh, const ushort_t* __restrict__ SEl,
    const ushort_t* __restrict__ ch, const ushort_t* __restrict__ cl,
    const float* __restrict__ c2,
    int* __restrict__ sc, float* __restrict__ out_w)
{
    __shared__ ushort_t lds[16384];
    __shared__ float c2s[512];
    __shared__ float redD[128][2];
    __shared__ int   redI[128][2];

    const int modal = blockIdx.y;
    const int t0 = blockIdx.x * 128;
    const int tid  = threadIdx.x;
    const int wave = tid >> 6, lane = tid & 63;
    const int wr = wave >> 1, wc = wave & 1;
    const int fr = lane & 15, fq = lane >> 4;

    const ushort_t* seh = SEh + (size_t)modal * NTOK * 256;
    const ushort_t* sel = SEl + (size_t)modal * NTOK * 256;

    c2s[tid] = c2[tid];
    c2s[tid + 256] = c2[tid + 256];

    int srow[2], sq[2], slbase[2];
    #pragma unroll
    for (int r = 0; r < 2; ++r) {
        int row = wave*32 + r*16 + (lane >> 2);
        srow[r]   = row;
        sq[r]     = (lane & 3) ^ ((row >> 1) & 3);
        slbase[r] = wave*1024 + r*512;
    }

    float bd[16]; int bi[16];
    #pragma unroll
    for (int s = 0; s < 16; ++s) { bd[s] = 3.4e38f; bi[s] = 0; }

    for (int j = 0; j < 4; ++j) {
        f32x4 acc[4][4] = {};
        for (int kt = 0; kt < 256; kt += 32) {
            __syncthreads();
            #pragma unroll
            for (int r = 0; r < 2; ++r) {
                size_t ga = (size_t)(t0 + srow[r]) * 256 + kt + sq[r]*8;
                size_t gc = (size_t)(j*128 + srow[r]) * 256 + kt + sq[r]*8;
                gload16(seh + ga, lds          + slbase[r]);
                gload16(sel + ga, lds + 4096   + slbase[r]);
                gload16(ch  + gc, lds + 8192   + slbase[r]);
                gload16(cl  + gc, lds + 12288  + slbase[r]);
            }
            __syncthreads();

            short8v ah[4], al[4], bh[4], bl[4];
            #pragma unroll
            for (int i = 0; i < 4; ++i) {
                int rowa = wr*64 + i*16 + fr;
                int offa = rowa*32 + ((fq ^ ((rowa >> 1) & 3)) * 8);
                ah[i] = *(const short8v*)(lds + offa);
                al[i] = *(const short8v*)(lds + 4096 + offa);
                int rowb = wc*64 + i*16 + fr;
                int offb = rowb*32 + ((fq ^ ((rowb >> 1) & 3)) * 8);
                bh[i] = *(const short8v*)(lds + 8192 + offb);
                bl[i] = *(const short8v*)(lds + 12288 + offb);
            }
            #pragma unroll
            for (int i = 0; i < 4; ++i)
                #pragma unroll
                for (int jj = 0; jj < 4; ++jj) {
                    acc[i][jj] = __builtin_amdgcn_mfma_f32_16x16x32_bf16(ah[i], bh[jj], acc[i][jj], 0, 0, 0);
                    acc[i][jj] = __builtin_amdgcn_mfma_f32_16x16x32_bf16(ah[i], bl[jj], acc[i][jj], 0, 0, 0);
                    acc[i][jj] = __builtin_amdgcn_mfma_f32_16x16x32_bf16(al[i], bh[jj], acc[i][jj], 0, 0, 0);
                }
        }
        #pragma unroll
        for (int i = 0; i < 4; ++i)
            #pragma unroll
            for (int jj = 0; jj < 4; ++jj) {
                int col = j*128 + wc*64 + jj*16 + fr;
                float cc = c2s[col];
                #pragma unroll
                for (int r = 0; r < 4; ++r) {
                    float d = cc - 2.f * acc[i][jj][r];
                    int s = i*4 + r;
                    if (d < bd[s]) { bd[s] = d; bi[s] = col; }
                }
            }
    }

    #pragma unroll
    for (int s = 0; s < 16; ++s) {
        #pragma unroll
        for (int off = 1; off < 16; off <<= 1) {
            float od = __shfl_xor(bd[s], off);
            int   oi = __shfl_xor(bi[s], off);
            if (od < bd[s] || (od == bd[s] && oi < bi[s])) { bd[s] = od; bi[s] = oi; }
        }
    }
    if (fr == 0) {
        #pragma unroll
        for (int i = 0; i < 4; ++i)
            #pragma unroll
            for (int r = 0; r < 4; ++r) {
                int tl = wr*64 + i*16 + fq*4 + r;
                redD[tl][wc] = bd[i*4 + r];
                redI[tl][wc] = bi[i*4 + r];
            }
    }
    __syncthreads();
    if (tid < 128) {
        float d0 = redD[tid][0], d1 = redD[tid][1];
        int   i0 = redI[tid][0], i1 = redI[tid][1];
        if (d1 < d0 || (d1 == d0 && i1 < i0)) { d0 = d1; i0 = i1; }
        int g = t0 + tid;
        sc[modal*NTOK + g] = i0;
        out_w[OFF_SC + (size_t)modal*NTOK + g] = (float)i0;
    }
}

// ---------------- fp32 fallback assignment ----------------
__global__ __launch_bounds__(256) void k_assign(
    const float* __restrict__ out_ro,
    const float* __restrict__ c2,
    int* __restrict__ sc,
    float* __restrict__ out_w)
{
    const int modal = blockIdx.y;
    const int tok0 = blockIdx.x * 64;
    const float* se   = out_ro + OFF_SE + (size_t)modal * NTOK * 256;
    const float* cent = out_ro + OFF_CENT;

    __shared__ float4 se4[64][64];
    __shared__ float4 ct4[64][64];

    const int tid = threadIdx.x;
    const int tt = tid & 15, cc = tid >> 4;

    {
        int rbase = tid >> 6;
        int d4 = tid & 63;
        #pragma unroll
        for (int i = 0; i < 16; ++i) {
            int t = i*4 + rbase;
            float4 v = *(const float4*)(se + (size_t)(tok0 + t)*256 + d4*4);
            se4[t][d4 ^ (t >> 2)] = v;
        }
    }
    __syncthreads();

    float e2r[4];
    #pragma unroll
    for (int k2 = 0; k2 < 4; ++k2) {
        float s = 0.f;
        for (int d4 = 0; d4 < 64; ++d4) {
            float4 v = se4[4*tt + k2][d4 ^ tt];
            s += dot4(v, v);
        }
        e2r[k2] = s;
    }

    float bd[4]; int bi[4];
    #pragma unroll
    for (int k2 = 0; k2 < 4; ++k2) { bd[k2] = 3.4e38f; bi[k2] = 0; }

    for (int ctile = 0; ctile < 8; ++ctile) {
        int c0 = ctile * 64;
        {
            int rbase = tid >> 6;
            int d4 = tid & 63;
            #pragma unroll
            for (int i = 0; i < 16; ++i) {
                int r = i*4 + rbase;
                float4 v = *(const float4*)(cent + (size_t)(c0 + r)*256 + d4*4);
                ct4[r][d4 ^ (r >> 2)] = v;
            }
        }
        __syncthreads();

        float accd[4][4];
        #pragma unroll
        for (int a = 0; a < 4; ++a)
            #pragma unroll
            for (int b = 0; b < 4; ++b) accd[a][b] = 0.f;

        for (int d4 = 0; d4 < 64; ++d4) {
            float4 sv[4], cv[4];
            #pragma unroll
            for (int k2 = 0; k2 < 4; ++k2) sv[k2] = se4[4*tt + k2][d4 ^ tt];
            #pragma unroll
            for (int jx = 0; jx < 4; ++jx) cv[jx] = ct4[4*cc + jx][d4 ^ cc];
            #pragma unroll
            for (int k2 = 0; k2 < 4; ++k2)
                #pragma unroll
                for (int jx = 0; jx < 4; ++jx)
                    accd[k2][jx] += dot4(sv[k2], cv[jx]);
        }

        #pragma unroll
        for (int jx = 0; jx < 4; ++jx) {
            int cidx = c0 + 4*cc + jx;
            float cj = c2[cidx];
            #pragma unroll
            for (int k2 = 0; k2 < 4; ++k2) {
                float d = cj + e2r[k2] - 2.f * accd[k2][jx];
                if (d < bd[k2]) { bd[k2] = d; bi[k2] = cidx; }
            }
        }
        __syncthreads();
    }

    float* red_d = (float*)ct4;
    int*   red_i = (int*)ct4 + 64*17;
    #pragma unroll
    for (int k2 = 0; k2 < 4; ++k2) {
        red_d[(4*tt + k2)*17 + cc] = bd[k2];
        red_i[(4*tt + k2)*17 + cc] = bi[k2];
    }
    __syncthreads();
    if (tid < 64) {
        float b = red_d[tid*17]; int ix = red_i[tid*17];
        #pragma unroll
        for (int q = 1; q < 16; ++q) {
            float d = red_d[tid*17 + q]; int i2 = red_i[tid*17 + q];
            if (d < b || (d == b && i2 < ix)) { b = d; ix = i2; }
        }
        int g = tok0 + tid;
        sc[modal*NTOK + g] = ix;
        out_w[OFF_SC + (size_t)modal*NTOK + g] = (float)ix;
    }
}

// ---------------- stable counting sort ----------------
__global__ __launch_bounds__(256) void k_hist(const int* __restrict__ sc,
                                              int* __restrict__ blockHist)
{
    int modal = blockIdx.y, blk = blockIdx.x, tid = threadIdx.x;
    __shared__ int h[512];
    h[tid] = 0; h[tid + 256] = 0;
    __syncthreads();
    atomicAdd(&h[sc[modal*NTOK + blk*256 + tid]], 1);
    __syncthreads();
    int base = (modal*128 + blk) * 512;
    blockHist[base + tid]       = h[tid];
    blockHist[base + tid + 256] = h[tid + 256];
}

__global__ __launch_bounds__(512) void k_scan(const int* __restrict__ blockHist,
                                              int* __restrict__ blockBase,
                                              int* __restrict__ classBase,
                                              float* __restrict__ out)
{
    int modal = blockIdx.x;
    int c = threadIdx.x;
    int run = 0;
    for (int b = 0; b < 128; ++b) {
        int idx = (modal*128 + b)*512 + c;
        blockBase[idx] = run;
        run += blockHist[idx];
    }
    float* cnt = out + (modal ? OFF_CI : OFF_CT);
    cnt[c] = (float)run;

    __shared__ int s[512];
    s[c] = run;
    __syncthreads();
    int total = run;
    for (int off = 1; off < 512; off <<= 1) {
        int v = 0;
        if (c >= off) v = s[c - off];
        __syncthreads();
        s[c] += v;
        __syncthreads();
    }
    classBase[modal*512 + c] = s[c] - total;
}

__global__ __launch_bounds__(256) void k_scatter(const int* __restrict__ sc,
                                                 const int* __restrict__ blockBase,
                                                 const int* __restrict__ classBase,
                                                 float* __restrict__ out)
{
    int modal = blockIdx.y, blk = blockIdx.x, tid = threadIdx.x;
    __shared__ int cls[256];
    int t = blk*256 + tid;
    int c = sc[modal*NTOK + t];
    cls[tid] = c;
    __syncthreads();
    int rank = 0;
    for (int j = 0; j < tid; ++j) rank += (cls[j] == c) ? 1 : 0;
    int pos = classBase[modal*512 + c] + blockBase[(modal*128 + blk)*512 + c] + rank;
    float* oo = out + (modal ? OFF_OI : OFF_OT);
    oo[pos] = (float)t;
}

extern "C" void kernel_launch(void* const* d_in, const int* in_sizes, int n_in,
                              void* d_out, int out_size, void* d_ws, size_t ws_size,
                              hipStream_t stream)
{
    const float* text_emb  = (const float*)d_in[0];
    const float* image_emb = (const float*)d_in[1];
    const float* W[2][3] = {
        {(const float*)d_in[2], (const float*)d_in[3], (const float*)d_in[4]},
        {(const float*)d_in[5], (const float*)d_in[6], (const float*)d_in[7]}
    };
    const float* cent_raw = (const float*)d_in[8];
    float* out = (float*)d_out;
    char* w = (char*)d_ws;

    int*   sc        = (int*)w;
    int*   blockHist = (int*)(w + 0x40000);
    int*   blockBase = (int*)(w + 0xC0000);
    int*   classBase = (int*)(w + 0x140000);
    float* c2        = (float*)(w + 0x141000);
    ushort_t* cent_h = (ushort_t*)(w + 0x142000);
    ushort_t* cent_l = (ushort_t*)(w + 0x182000);

    ushort_t* wreg = (ushort_t*)(w + 0x200000);
    const size_t WM = 4*1048576 + 2*262144;

    ushort_t* SEh = (ushort_t*)(w + 0x1400000);
    ushort_t* SEl = (ushort_t*)(w + 0x3400000);

    bool mfmaAssign = true;
    size_t actoff = 0x5400000;
    int Mc = 0;
    for (int c = NTOK; c >= 128; c >>= 1)
        if (actoff + (size_t)c*8192 <= ws_size) { Mc = c; break; }
    if (Mc == 0) {
        mfmaAssign = false;
        actoff = 0x1400000;
        for (int c = NTOK; c >= 128; c >>= 1)
            if (actoff + (size_t)c*8192 <= ws_size) { Mc = c; break; }
        if (Mc == 0) Mc = 128;
    }
    ushort_t* act = (ushort_t*)(w + actoff);
    const bool big = (Mc % 256 == 0);

    k_cent<<<dim3(512), dim3(64), 0, stream>>>(cent_raw, out, c2, cent_h, cent_l);
    k_wc  <<<dim3(64),  dim3(256), 0, stream>>>(out);

    for (int m = 0; m < 2; ++m) {
        const float* emb = m ? image_emb : text_emb;
        ushort_t* w1h = wreg + (size_t)m*WM;
        ushort_t* w1l = w1h + 1048576;
        ushort_t* w2h = w1l + 1048576;
        ushort_t* w2l = w2h + 1048576;
        ushort_t* w3h = w2l + 1048576;
        ushort_t* w3l = w3h + 262144;

        k_wsplit<<<dim3(32, 32), dim3(256), 0, stream>>>(W[m][0], w1h, w1l, 1024, 1024);
        k_wsplit<<<dim3(32, 32), dim3(256), 0, stream>>>(W[m][1], w2h, w2l, 1024, 1024);
        k_wsplit<<<dim3(8,  32), dim3(256), 0, stream>>>(W[m][2], w3h, w3l, 1024, 256);

        ushort_t* Ah = act;
        ushort_t* Al = Ah + (size_t)Mc*1024;
        ushort_t* Hh = Al + (size_t)Mc*1024;
        ushort_t* Hl = Hh + (size_t)Mc*1024;

        for (int s0 = 0; s0 < NTOK; s0 += Mc) {
            long n4 = (long)Mc*1024/4;
            k_esplit<<<dim3((unsigned)((n4 + 255)/256)), dim3(256), 0, stream>>>(
                emb + (size_t)s0*1024, Ah, Al, n4);
            if (big) {
                k_gemm_mfma256<<<dim3((Mc/256)*4), dim3(512), 0, stream>>>(
                    Ah, Al, w1h, w1l, Hh, Hl, 1024);
                k_gemm_mfma256<<<dim3((Mc/256)*4), dim3(512), 0, stream>>>(
                    Hh, Hl, w2h, w2l, Ah, Al, 1024);
            } else {
                k_gemm_mfma<<<dim3(8, Mc/128), dim3(256), 0, stream>>>(
                    Ah, Al, w1h, w1l, Hh, Hl, nullptr, 1024);
                k_gemm_mfma<<<dim3(8, Mc/128), dim3(256), 0, stream>>>(
                    Hh, Hl, w2h, w2l, Ah, Al, nullptr, 1024);
            }
            ushort_t* seh_ptr = mfmaAssign ? SEh + ((size_t)m*NTOK + s0)*256 : nullptr;
            ushort_t* sel_ptr = mfmaAssign ? SEl + ((size_t)m*NTOK + s0)*256 : nullptr;
            k_gemm_mfma<<<dim3(2, Mc/128), dim3(256), 0, stream>>>(
                Ah, Al, w3h, w3l, seh_ptr, sel_ptr,
                out + OFF_SE + ((size_t)m*NTOK + s0)*256, 256);
        }
    }

    if (mfmaAssign) {
        k_assign_mfma<<<dim3(256, 2), dim3(256), 0, stream>>>(
            SEh, SEl, cent_h, cent_l, c2, sc, out);
    } else {
        k_assign<<<dim3(512, 2), dim3(256), 0, stream>>>(out, c2, sc, out);
    }
    k_hist   <<<dim3(128, 2), dim3(256), 0, stream>>>(sc, blockHist);
    k_scan   <<<dim3(2),      dim3(512), 0, stream>>>(blockHist, blockBase, classBase, out);
    k_scatter<<<dim3(128, 2), dim3(256), 0, stream>>>(sc, blockBase, classBase, out);
}

// Round 5
// 1089.492 us; speedup vs baseline: 3.6642x; 1.0645x over previous
//
#include <hip/hip_runtime.h>
#include <math.h>

#define NTOK 32768
typedef unsigned short ushort_t;

// d_out offsets (in floats)
#define OFF_CENT 0
#define OFF_SE   131072
#define OFF_WC   16908288
#define OFF_SC   16973824
#define OFF_OT   17039360
#define OFF_CT   17072128
#define OFF_OI   17072640
#define OFF_CI   17105408

typedef __attribute__((ext_vector_type(8))) short short8v;
typedef __attribute__((ext_vector_type(4))) float f32x4;

__device__ __forceinline__ float dot4(float4 a, float4 b){
    return a.x*b.x + a.y*b.y + a.z*b.z + a.w*b.w;
}

// RNE float -> bf16 bits
__device__ __forceinline__ ushort_t f2bf(float x){
    unsigned int u = __float_as_uint(x);
    unsigned int r = (u + 0x7fffu + ((u >> 16) & 1u)) >> 16;
    return (ushort_t)r;
}
__device__ __forceinline__ float bf2f(ushort_t h){
    return __uint_as_float(((unsigned int)h) << 16);
}

__device__ __forceinline__ void gload16(const void* g, void* l){
    __builtin_amdgcn_global_load_lds(
        (const __attribute__((address_space(1))) void*)g,
        (__attribute__((address_space(3))) void*)l,
        16, 0, 0);
}

// ---------------- centroids: tanh + c2 + hi/lo split ----------------
__global__ __launch_bounds__(64) void k_cent(const float* __restrict__ raw,
                                             float* __restrict__ out,
                                             float* __restrict__ c2,
                                             ushort_t* __restrict__ ch,
                                             ushort_t* __restrict__ cl)
{
    int c = blockIdx.x, l = threadIdx.x;
    float4 v = *(const float4*)(raw + (size_t)c*256 + l*4);
    float4 t;
    t.x = tanhf(v.x); t.y = tanhf(v.y); t.z = tanhf(v.z); t.w = tanhf(v.w);
    *(float4*)(out + OFF_CENT + (size_t)c*256 + l*4) = t;
    ushort4 h = make_ushort4(f2bf(t.x), f2bf(t.y), f2bf(t.z), f2bf(t.w));
    ushort4 lo = make_ushort4(f2bf(t.x - bf2f(h.x)), f2bf(t.y - bf2f(h.y)),
                              f2bf(t.z - bf2f(h.z)), f2bf(t.w - bf2f(h.w)));
    *(ushort4*)(ch + (size_t)c*256 + l*4) = h;
    *(ushort4*)(cl + (size_t)c*256 + l*4) = lo;
    float s = dot4(t, t);
    #pragma unroll
    for (int off = 32; off > 0; off >>= 1) s += __shfl_down(s, off);
    if (l == 0) c2[c] = s;
}

// ---------------- word_class fill ----------------
__global__ __launch_bounds__(256) void k_wc(float* __restrict__ out)
{
    int g = blockIdx.x*256 + threadIdx.x;
    float v = (g*4 < NTOK) ? 0.f : 1.f;
    float4* p = (float4*)(out + OFF_WC);
    p[g] = make_float4(v, v, v, v);
}

// ---------------- emb split: fp32 -> (hi,lo) bf16 ----------------
__global__ __launch_bounds__(256) void k_esplit(const float* __restrict__ x,
                                                ushort_t* __restrict__ hi,
                                                ushort_t* __restrict__ lo,
                                                long n4)
{
    long g = (long)blockIdx.x*256 + threadIdx.x;
    if (g >= n4) return;
    float4 v = ((const float4*)x)[g];
    ushort_t h0 = f2bf(v.x), h1 = f2bf(v.y), h2 = f2bf(v.z), h3 = f2bf(v.w);
    ushort4 h = make_ushort4(h0, h1, h2, h3);
    ushort4 l = make_ushort4(f2bf(v.x - bf2f(h0)), f2bf(v.y - bf2f(h1)),
                             f2bf(v.z - bf2f(h2)), f2bf(v.w - bf2f(h3)));
    ((ushort4*)hi)[g] = h;
    ((ushort4*)lo)[g] = l;
}

// ---------------- weight transpose + split ----------------
__global__ __launch_bounds__(256) void k_wsplit(const float* __restrict__ W,
                                                ushort_t* __restrict__ Wt_hi,
                                                ushort_t* __restrict__ Wt_lo,
                                                int K, int N)
{
    __shared__ float t[32][33];
    int k0 = blockIdx.y*32, n0 = blockIdx.x*32;
    int tx = threadIdx.x & 31, ty = threadIdx.x >> 5;
    #pragma unroll
    for (int r = 0; r < 4; ++r)
        t[ty + r*8][tx] = W[(size_t)(k0 + ty + r*8)*N + n0 + tx];
    __syncthreads();
    #pragma unroll
    for (int r = 0; r < 4; ++r) {
        int n = ty + r*8;
        float x = t[tx][n];
        ushort_t h = f2bf(x);
        Wt_hi[(size_t)(n0+n)*K + k0 + tx] = h;
        Wt_lo[(size_t)(n0+n)*K + k0 + tx] = f2bf(x - bf2f(h));
    }
}

// ================= 256x256 8-wave split-bf16 GEMM + tanh (1 barrier / K-tile) ==========
// C = tanh((A_hi+A_lo)[M,1024] @ (B_hi+B_lo)^T), Bt [N][1024]. K=1024. BK=32.
// A_lo = A_hi + aDelta; Bt_lo = Bt_hi + bDelta (contiguous allocations).
// 512 threads = 8 waves (2M x 4N), per-wave 128x64 output. LDS 128 KiB (2 full bufs).
__global__ __launch_bounds__(512, 2) void k_gemm_mfma256(
    const ushort_t* __restrict__ A_hi, const ushort_t* __restrict__ Bt_hi,
    ushort_t* __restrict__ C_hi, ushort_t* __restrict__ C_lo,
    unsigned aDelta, unsigned bDelta, int N)
{
    __shared__ ushort_t lds[65536];   // 2 x { Ah[256][32] Al Bh Bl } (8192 elems each)

    const int tid  = threadIdx.x;
    const int wave = tid >> 6, lane = tid & 63;
    const int wr = wave >> 2, wc = wave & 3;
    const int fr = lane & 15, fq = lane >> 4;

    // T1: bijective XCD swizzle (nwg % 8 == 0 for all uses here)
    int nwg = gridDim.x;
    int id = blockIdx.x;
    if (!(nwg & 7)) { int cpx = nwg >> 3; id = (id & 7)*cpx + (id >> 3); }
    const int nx = N >> 8;
    const int n0 = (id % nx) * 256;
    const int m0 = (id / nx) * 256;

    // staging: thread t covers rows (t>>2) and (t>>2)+128, k-slot t&3, pre-swizzled source
    const int srow0 = tid >> 2;
    const int qx = (tid & 3) ^ ((srow0 >> 1) & 3);

    // hoisted per-thread global pointers (64-bit mul done once)
    const unsigned offA0 = (unsigned)(m0 + srow0) * 1024u + (unsigned)qx * 8u;
    const unsigned offB0 = (unsigned)(n0 + srow0) * 1024u + (unsigned)qx * 8u;
    const ushort_t* pA0  = A_hi + offA0;
    const ushort_t* pA1  = pA0 + 131072u;          // +128 rows
    const ushort_t* pA0l = pA0 + aDelta;
    const ushort_t* pA1l = pA1 + aDelta;
    const ushort_t* pB0  = Bt_hi + offB0;
    const ushort_t* pB1  = pB0 + 131072u;
    const ushort_t* pB0l = pB0 + bDelta;
    const ushort_t* pB1l = pB1 + bDelta;
    const unsigned ldsS0 = (unsigned)wave * 512u;  // rows wave*16.., r=0 half
    const unsigned ldsS1 = ldsS0 + 4096u;          // +128 rows

    // fragment read base: row=fr within frag, XOR k-slot is lane-only
    const unsigned fbase = (unsigned)fr*32u + (unsigned)((fq ^ ((fr >> 1) & 3)) * 8);

    f32x4 acc[8][4] = {};

#define STG(KT, WB) { \
    unsigned wb_ = (unsigned)(WB) * 32768u; \
    gload16(pA0  + (KT), lds + wb_ +           ldsS0); \
    gload16(pA1  + (KT), lds + wb_ +           ldsS1); \
    gload16(pA0l + (KT), lds + wb_ +  8192u +  ldsS0); \
    gload16(pA1l + (KT), lds + wb_ +  8192u +  ldsS1); \
    gload16(pB0  + (KT), lds + wb_ + 16384u +  ldsS0); \
    gload16(pB1  + (KT), lds + wb_ + 16384u +  ldsS1); \
    gload16(pB0l + (KT), lds + wb_ + 24576u +  ldsS0); \
    gload16(pB1l + (KT), lds + wb_ + 24576u +  ldsS1); \
}

#define LDA(i, hl) (*(const short8v*)(lds + rb + (hl)*8192u + (unsigned)wr*4096u + (i)*512u + fbase))
#define LDB(j, hl) (*(const short8v*)(lds + rb + 16384u + (hl)*8192u + (unsigned)wc*2048u + (j)*512u + fbase))

#define MF(I, AH, AL, J, BH, BL) \
    acc[I][J] = __builtin_amdgcn_mfma_f32_16x16x32_bf16(AH, BH, acc[I][J], 0, 0, 0); \
    acc[I][J] = __builtin_amdgcn_mfma_f32_16x16x32_bf16(AH, BL, acc[I][J], 0, 0, 0); \
    acc[I][J] = __builtin_amdgcn_mfma_f32_16x16x32_bf16(AL, BH, acc[I][J], 0, 0, 0);

#define MFROW2(I0, I1) \
    MF(I0, c0h, c0l, 0, bh0, bl0) MF(I0, c0h, c0l, 1, bh1, bl1) \
    MF(I0, c0h, c0l, 2, bh2, bl2) MF(I0, c0h, c0l, 3, bh3, bl3) \
    MF(I1, c1h, c1l, 0, bh0, bl0) MF(I1, c1h, c1l, 1, bh1, bl1) \
    MF(I1, c1h, c1l, 2, bh2, bl2) MF(I1, c1h, c1l, 3, bh3, bl3)

    // prologue: stage tile 0 into buf 0
    STG(0, 0);
    __syncthreads();

    #pragma unroll 1
    for (int kt = 0; kt < 1024; kt += 32) {
        const unsigned rb = ((unsigned)(kt >> 5) & 1u) * 32768u;

        // stage next tile into other buffer (in-flight across the whole tile's compute)
        if (kt + 32 < 1024) STG(kt + 32, ((kt >> 5) & 1) ^ 1);

        // whole-tile B fragments + first A pair
        short8v bh0 = LDB(0,0), bl0 = LDB(0,1);
        short8v bh1 = LDB(1,0), bl1 = LDB(1,1);
        short8v bh2 = LDB(2,0), bl2 = LDB(2,1);
        short8v bh3 = LDB(3,0), bl3 = LDB(3,1);
        short8v c0h = LDA(0,0), c0l = LDA(0,1), c1h = LDA(1,0), c1l = LDA(1,1);
        short8v n0h, n0l, n1h, n1l;

        // phase 0: prefetch A(2,3), MFMA rows 0,1
        n0h = LDA(2,0); n0l = LDA(2,1); n1h = LDA(3,0); n1l = LDA(3,1);
        __builtin_amdgcn_s_setprio(1);
        MFROW2(0, 1)
        __builtin_amdgcn_s_setprio(0);
        c0h = n0h; c0l = n0l; c1h = n1h; c1l = n1l;

        // phase 1: prefetch A(4,5), MFMA rows 2,3
        n0h = LDA(4,0); n0l = LDA(4,1); n1h = LDA(5,0); n1l = LDA(5,1);
        __builtin_amdgcn_s_setprio(1);
        MFROW2(2, 3)
        __builtin_amdgcn_s_setprio(0);
        c0h = n0h; c0l = n0l; c1h = n1h; c1l = n1l;

        // phase 2: prefetch A(6,7), MFMA rows 4,5
        n0h = LDA(6,0); n0l = LDA(6,1); n1h = LDA(7,0); n1l = LDA(7,1);
        __builtin_amdgcn_s_setprio(1);
        MFROW2(4, 5)
        __builtin_amdgcn_s_setprio(0);
        c0h = n0h; c0l = n0l; c1h = n1h; c1l = n1l;

        // phase 3: MFMA rows 6,7
        __builtin_amdgcn_s_setprio(1);
        MFROW2(6, 7)
        __builtin_amdgcn_s_setprio(0);

        // single boundary barrier: drains staging (vmcnt 0) + read/write separation
        __syncthreads();
    }

    // epilogue: C/D layout col = lane&15, row = (lane>>4)*4 + reg
    #pragma unroll
    for (int i = 0; i < 8; ++i)
        #pragma unroll
        for (int j = 0; j < 4; ++j)
            #pragma unroll
            for (int r = 0; r < 4; ++r) {
                int row = m0 + wr*128 + i*16 + fq*4 + r;
                int col = n0 + wc*64 + j*16 + fr;
                float t = tanhf(acc[i][j][r]);
                size_t idx = (size_t)row*N + col;
                ushort_t h = f2bf(t);
                C_hi[idx] = h;
                C_lo[idx] = f2bf(t - bf2f(h));
            }
#undef STG
#undef LDA
#undef LDB
#undef MF
#undef MFROW2
}

// ---------------- 128x128 split-bf16 MFMA GEMM + tanh (layer 3 / fallback) ----------------
__global__ __launch_bounds__(256, 2) void k_gemm_mfma(
    const ushort_t* __restrict__ A_hi, const ushort_t* __restrict__ A_lo,
    const ushort_t* __restrict__ Bt_hi, const ushort_t* __restrict__ Bt_lo,
    ushort_t* __restrict__ C_hi, ushort_t* __restrict__ C_lo,
    float* __restrict__ Cf,
    int N)
{
    const int K = 1024;
    __shared__ ushort_t lds[16384];

    const int tid  = threadIdx.x;
    const int wave = tid >> 6, lane = tid & 63;
    const int wr = wave >> 1, wc = wave & 1;

    int nwg = gridDim.x * gridDim.y;
    int id = blockIdx.y * gridDim.x + blockIdx.x;
    if (!(nwg & 7)) { int cpx = nwg >> 3; id = (id & 7)*cpx + (id >> 3); }
    const int m0 = (id / gridDim.x) * 128, n0 = (id % gridDim.x) * 128;

    f32x4 acc[4][4] = {};

    int srow[2], sq[2], slbase[2];
    #pragma unroll
    for (int r = 0; r < 2; ++r) {
        int row = wave*32 + r*16 + (lane >> 2);
        srow[r]   = row;
        sq[r]     = (lane & 3) ^ ((row >> 1) & 3);
        slbase[r] = wave*1024 + r*512;
    }

    const int fr = lane & 15, fq = lane >> 4;

    for (int kt = 0; kt < K; kt += 32) {
        __syncthreads();
        #pragma unroll
        for (int r = 0; r < 2; ++r) {
            size_t ga = (size_t)(m0 + srow[r]) * K + kt + sq[r]*8;
            size_t gb = (size_t)(n0 + srow[r]) * K + kt + sq[r]*8;
            gload16(A_hi  + ga, lds          + slbase[r]);
            gload16(A_lo  + ga, lds + 4096   + slbase[r]);
            gload16(Bt_hi + gb, lds + 8192   + slbase[r]);
            gload16(Bt_lo + gb, lds + 12288  + slbase[r]);
        }
        __syncthreads();

        short8v ah[4], al[4], bh[4], bl[4];
        #pragma unroll
        for (int i = 0; i < 4; ++i) {
            int rowa = wr*64 + i*16 + fr;
            int offa = rowa*32 + ((fq ^ ((rowa >> 1) & 3)) * 8);
            ah[i] = *(const short8v*)(lds + offa);
            al[i] = *(const short8v*)(lds + 4096 + offa);
            int rowb = wc*64 + i*16 + fr;
            int offb = rowb*32 + ((fq ^ ((rowb >> 1) & 3)) * 8);
            bh[i] = *(const short8v*)(lds + 8192 + offb);
            bl[i] = *(const short8v*)(lds + 12288 + offb);
        }
        #pragma unroll
        for (int i = 0; i < 4; ++i)
            #pragma unroll
            for (int j = 0; j < 4; ++j) {
                acc[i][j] = __builtin_amdgcn_mfma_f32_16x16x32_bf16(ah[i], bh[j], acc[i][j], 0, 0, 0);
                acc[i][j] = __builtin_amdgcn_mfma_f32_16x16x32_bf16(ah[i], bl[j], acc[i][j], 0, 0, 0);
                acc[i][j] = __builtin_amdgcn_mfma_f32_16x16x32_bf16(al[i], bh[j], acc[i][j], 0, 0, 0);
            }
    }

    #pragma unroll
    for (int i = 0; i < 4; ++i)
        #pragma unroll
        for (int j = 0; j < 4; ++j)
            #pragma unroll
            for (int r = 0; r < 4; ++r) {
                int row = m0 + wr*64 + i*16 + fq*4 + r;
                int col = n0 + wc*64 + j*16 + fr;
                float t = tanhf(acc[i][j][r]);
                size_t idx = (size_t)row*N + col;
                if (Cf) Cf[idx] = t;
                if (C_hi) {
                    ushort_t h = f2bf(t);
                    C_hi[idx] = h;
                    C_lo[idx] = f2bf(t - bf2f(h));
                }
            }
}

// ---------------- MFMA assignment: argmin_c (c2[c] - 2 * se.cent) ----------------
__global__ __launch_bounds__(256) void k_assign_mfma(
    const ushort_t* __restrict__ SEh, const ushort_t* __restrict__ SEl,
    const ushort_t* __restrict__ ch, const ushort_t* __restrict__ cl,
    const float* __restrict__ c2,
    int* __restrict__ sc, float* __restrict__ out_w)
{
    __shared__ ushort_t lds[16384];
    __shared__ float c2s[512];
    __shared__ float redD[128][2];
    __shared__ int   redI[128][2];

    const int modal = blockIdx.y;
    const int t0 = blockIdx.x * 128;
    const int tid  = threadIdx.x;
    const int wave = tid >> 6, lane = tid & 63;
    const int wr = wave >> 1, wc = wave & 1;
    const int fr = lane & 15, fq = lane >> 4;

    const ushort_t* seh = SEh + (size_t)modal * NTOK * 256;
    const ushort_t* sel = SEl + (size_t)modal * NTOK * 256;

    c2s[tid] = c2[tid];
    c2s[tid + 256] = c2[tid + 256];

    int srow[2], sq[2], slbase[2];
    #pragma unroll
    for (int r = 0; r < 2; ++r) {
        int row = wave*32 + r*16 + (lane >> 2);
        srow[r]   = row;
        sq[r]     = (lane & 3) ^ ((row >> 1) & 3);
        slbase[r] = wave*1024 + r*512;
    }

    float bd[16]; int bi[16];
    #pragma unroll
    for (int s = 0; s < 16; ++s) { bd[s] = 3.4e38f; bi[s] = 0; }

    for (int j = 0; j < 4; ++j) {
        f32x4 acc[4][4] = {};
        for (int kt = 0; kt < 256; kt += 32) {
            __syncthreads();
            #pragma unroll
            for (int r = 0; r < 2; ++r) {
                size_t ga = (size_t)(t0 + srow[r]) * 256 + kt + sq[r]*8;
                size_t gc = (size_t)(j*128 + srow[r]) * 256 + kt + sq[r]*8;
                gload16(seh + ga, lds          + slbase[r]);
                gload16(sel + ga, lds + 4096   + slbase[r]);
                gload16(ch  + gc, lds + 8192   + slbase[r]);
                gload16(cl  + gc, lds + 12288  + slbase[r]);
            }
            __syncthreads();

            short8v ah[4], al[4], bh[4], bl[4];
            #pragma unroll
            for (int i = 0; i < 4; ++i) {
                int rowa = wr*64 + i*16 + fr;
                int offa = rowa*32 + ((fq ^ ((rowa >> 1) & 3)) * 8);
                ah[i] = *(const short8v*)(lds + offa);
                al[i] = *(const short8v*)(lds + 4096 + offa);
                int rowb = wc*64 + i*16 + fr;
                int offb = rowb*32 + ((fq ^ ((rowb >> 1) & 3)) * 8);
                bh[i] = *(const short8v*)(lds + 8192 + offb);
                bl[i] = *(const short8v*)(lds + 12288 + offb);
            }
            #pragma unroll
            for (int i = 0; i < 4; ++i)
                #pragma unroll
                for (int jj = 0; jj < 4; ++jj) {
                    acc[i][jj] = __builtin_amdgcn_mfma_f32_16x16x32_bf16(ah[i], bh[jj], acc[i][jj], 0, 0, 0);
                    acc[i][jj] = __builtin_amdgcn_mfma_f32_16x16x32_bf16(ah[i], bl[jj], acc[i][jj], 0, 0, 0);
                    acc[i][jj] = __builtin_amdgcn_mfma_f32_16x16x32_bf16(al[i], bh[jj], acc[i][jj], 0, 0, 0);
                }
        }
        #pragma unroll
        for (int i = 0; i < 4; ++i)
            #pragma unroll
            for (int jj = 0; jj < 4; ++jj) {
                int col = j*128 + wc*64 + jj*16 + fr;
                float cc = c2s[col];
                #pragma unroll
                for (int r = 0; r < 4; ++r) {
                    float d = cc - 2.f * acc[i][jj][r];
                    int s = i*4 + r;
                    if (d < bd[s]) { bd[s] = d; bi[s] = col; }
                }
            }
    }

    #pragma unroll
    for (int s = 0; s < 16; ++s) {
        #pragma unroll
        for (int off = 1; off < 16; off <<= 1) {
            float od = __shfl_xor(bd[s], off);
            int   oi = __shfl_xor(bi[s], off);
            if (od < bd[s] || (od == bd[s] && oi < bi[s])) { bd[s] = od; bi[s] = oi; }
        }
    }
    if (fr == 0) {
        #pragma unroll
        for (int i = 0; i < 4; ++i)
            #pragma unroll
            for (int r = 0; r < 4; ++r) {
                int tl = wr*64 + i*16 + fq*4 + r;
                redD[tl][wc] = bd[i*4 + r];
                redI[tl][wc] = bi[i*4 + r];
            }
    }
    __syncthreads();
    if (tid < 128) {
        float d0 = redD[tid][0], d1 = redD[tid][1];
        int   i0 = redI[tid][0], i1 = redI[tid][1];
        if (d1 < d0 || (d1 == d0 && i1 < i0)) { d0 = d1; i0 = i1; }
        int g = t0 + tid;
        sc[modal*NTOK + g] = i0;
        out_w[OFF_SC + (size_t)modal*NTOK + g] = (float)i0;
    }
}

// ---------------- fp32 fallback assignment ----------------
__global__ __launch_bounds__(256) void k_assign(
    const float* __restrict__ out_ro,
    const float* __restrict__ c2,
    int* __restrict__ sc,
    float* __restrict__ out_w)
{
    const int modal = blockIdx.y;
    const int tok0 = blockIdx.x * 64;
    const float* se   = out_ro + OFF_SE + (size_t)modal * NTOK * 256;
    const float* cent = out_ro + OFF_CENT;

    __shared__ float4 se4[64][64];
    __shared__ float4 ct4[64][64];

    const int tid = threadIdx.x;
    const int tt = tid & 15, cc = tid >> 4;

    {
        int rbase = tid >> 6;
        int d4 = tid & 63;
        #pragma unroll
        for (int i = 0; i < 16; ++i) {
            int t = i*4 + rbase;
            float4 v = *(const float4*)(se + (size_t)(tok0 + t)*256 + d4*4);
            se4[t][d4 ^ (t >> 2)] = v;
        }
    }
    __syncthreads();

    float e2r[4];
    #pragma unroll
    for (int k2 = 0; k2 < 4; ++k2) {
        float s = 0.f;
        for (int d4 = 0; d4 < 64; ++d4) {
            float4 v = se4[4*tt + k2][d4 ^ tt];
            s += dot4(v, v);
        }
        e2r[k2] = s;
    }

    float bd[4]; int bi[4];
    #pragma unroll
    for (int k2 = 0; k2 < 4; ++k2) { bd[k2] = 3.4e38f; bi[k2] = 0; }

    for (int ctile = 0; ctile < 8; ++ctile) {
        int c0 = ctile * 64;
        {
            int rbase = tid >> 6;
            int d4 = tid & 63;
            #pragma unroll
            for (int i = 0; i < 16; ++i) {
                int r = i*4 + rbase;
                float4 v = *(const float4*)(cent + (size_t)(c0 + r)*256 + d4*4);
                ct4[r][d4 ^ (r >> 2)] = v;
            }
        }
        __syncthreads();

        float accd[4][4];
        #pragma unroll
        for (int a = 0; a < 4; ++a)
            #pragma unroll
            for (int b = 0; b < 4; ++b) accd[a][b] = 0.f;

        for (int d4 = 0; d4 < 64; ++d4) {
            float4 sv[4], cv[4];
            #pragma unroll
            for (int k2 = 0; k2 < 4; ++k2) sv[k2] = se4[4*tt + k2][d4 ^ tt];
            #pragma unroll
            for (int jx = 0; jx < 4; ++jx) cv[jx] = ct4[4*cc + jx][d4 ^ cc];
            #pragma unroll
            for (int k2 = 0; k2 < 4; ++k2)
                #pragma unroll
                for (int jx = 0; jx < 4; ++jx)
                    accd[k2][jx] += dot4(sv[k2], cv[jx]);
        }

        #pragma unroll
        for (int jx = 0; jx < 4; ++jx) {
            int cidx = c0 + 4*cc + jx;
            float cj = c2[cidx];
            #pragma unroll
            for (int k2 = 0; k2 < 4; ++k2) {
                float d = cj + e2r[k2] - 2.f * accd[k2][jx];
                if (d < bd[k2]) { bd[k2] = d; bi[k2] = cidx; }
            }
        }
        __syncthreads();
    }

    float* red_d = (float*)ct4;
    int*   red_i = (int*)ct4 + 64*17;
    #pragma unroll
    for (int k2 = 0; k2 < 4; ++k2) {
        red_d[(4*tt + k2)*17 + cc] = bd[k2];
        red_i[(4*tt + k2)*17 + cc] = bi[k2];
    }
    __syncthreads();
    if (tid < 64) {
        float b = red_d[tid*17]; int ix = red_i[tid*17];
        #pragma unroll
        for (int q = 1; q < 16; ++q) {
            float d = red_d[tid*17 + q]; int i2 = red_i[tid*17 + q];
            if (d < b || (d == b && i2 < ix)) { b = d; ix = i2; }
        }
        int g = tok0 + tid;
        sc[modal*NTOK + g] = ix;
        out_w[OFF_SC + (size_t)modal*NTOK + g] = (float)ix;
    }
}

// ---------------- stable counting sort ----------------
__global__ __launch_bounds__(256) void k_hist(const int* __restrict__ sc,
                                              int* __restrict__ blockHist)
{
    int modal = blockIdx.y, blk = blockIdx.x, tid = threadIdx.x;
    __shared__ int h[512];
    h[tid] = 0; h[tid + 256] = 0;
    __syncthreads();
    atomicAdd(&h[sc[modal*NTOK + blk*256 + tid]], 1);
    __syncthreads();
    int base = (modal*128 + blk) * 512;
    blockHist[base + tid]       = h[tid];
    blockHist[base + tid + 256] = h[tid + 256];
}

__global__ __launch_bounds__(512) void k_scan(const int* __restrict__ blockHist,
                                              int* __restrict__ blockBase,
                                              int* __restrict__ classBase,
                                              float* __restrict__ out)
{
    int modal = blockIdx.x;
    int c = threadIdx.x;
    int run = 0;
    for (int b = 0; b < 128; ++b) {
        int idx = (modal*128 + b)*512 + c;
        blockBase[idx] = run;
        run += blockHist[idx];
    }
    float* cnt = out + (modal ? OFF_CI : OFF_CT);
    cnt[c] = (float)run;

    __shared__ int s[512];
    s[c] = run;
    __syncthreads();
    int total = run;
    for (int off = 1; off < 512; off <<= 1) {
        int v = 0;
        if (c >= off) v = s[c - off];
        __syncthreads();
        s[c] += v;
        __syncthreads();
    }
    classBase[modal*512 + c] = s[c] - total;
}

__global__ __launch_bounds__(256) void k_scatter(const int* __restrict__ sc,
                                                 const int* __restrict__ blockBase,
                                                 const int* __restrict__ classBase,
                                                 float* __restrict__ out)
{
    int modal = blockIdx.y, blk = blockIdx.x, tid = threadIdx.x;
    __shared__ int cls[256];
    int t = blk*256 + tid;
    int c = sc[modal*NTOK + t];
    cls[tid] = c;
    __syncthreads();
    int rank = 0;
    for (int j = 0; j < tid; ++j) rank += (cls[j] == c) ? 1 : 0;
    int pos = classBase[modal*512 + c] + blockBase[(modal*128 + blk)*512 + c] + rank;
    float* oo = out + (modal ? OFF_OI : OFF_OT);
    oo[pos] = (float)t;
}

extern "C" void kernel_launch(void* const* d_in, const int* in_sizes, int n_in,
                              void* d_out, int out_size, void* d_ws, size_t ws_size,
                              hipStream_t stream)
{
    const float* text_emb  = (const float*)d_in[0];
    const float* image_emb = (const float*)d_in[1];
    const float* W[2][3] = {
        {(const float*)d_in[2], (const float*)d_in[3], (const float*)d_in[4]},
        {(const float*)d_in[5], (const float*)d_in[6], (const float*)d_in[7]}
    };
    const float* cent_raw = (const float*)d_in[8];
    float* out = (float*)d_out;
    char* w = (char*)d_ws;

    int*   sc        = (int*)w;
    int*   blockHist = (int*)(w + 0x40000);
    int*   blockBase = (int*)(w + 0xC0000);
    int*   classBase = (int*)(w + 0x140000);
    float* c2        = (float*)(w + 0x141000);
    ushort_t* cent_h = (ushort_t*)(w + 0x142000);
    ushort_t* cent_l = (ushort_t*)(w + 0x182000);

    ushort_t* wreg = (ushort_t*)(w + 0x200000);
    const size_t WM = 4*1048576 + 2*262144;

    ushort_t* SEh = (ushort_t*)(w + 0x1400000);
    ushort_t* SEl = (ushort_t*)(w + 0x3400000);

    bool mfmaAssign = true;
    size_t actoff = 0x5400000;
    int Mc = 0;
    for (int c = NTOK; c >= 128; c >>= 1)
        if (actoff + (size_t)c*8192 <= ws_size) { Mc = c; break; }
    if (Mc == 0) {
        mfmaAssign = false;
        actoff = 0x1400000;
        for (int c = NTOK; c >= 128; c >>= 1)
            if (actoff + (size_t)c*8192 <= ws_size) { Mc = c; break; }
        if (Mc == 0) Mc = 128;
    }
    ushort_t* act = (ushort_t*)(w + actoff);
    const bool big = (Mc % 256 == 0);

    k_cent<<<dim3(512), dim3(64), 0, stream>>>(cent_raw, out, c2, cent_h, cent_l);
    k_wc  <<<dim3(64),  dim3(256), 0, stream>>>(out);

    for (int m = 0; m < 2; ++m) {
        const float* emb = m ? image_emb : text_emb;
        ushort_t* w1h = wreg + (size_t)m*WM;
        ushort_t* w1l = w1h + 1048576;
        ushort_t* w2h = w1l + 1048576;
        ushort_t* w2l = w2h + 1048576;
        ushort_t* w3h = w2l + 1048576;
        ushort_t* w3l = w3h + 262144;

        k_wsplit<<<dim3(32, 32), dim3(256), 0, stream>>>(W[m][0], w1h, w1l, 1024, 1024);
        k_wsplit<<<dim3(32, 32), dim3(256), 0, stream>>>(W[m][1], w2h, w2l, 1024, 1024);
        k_wsplit<<<dim3(8,  32), dim3(256), 0, stream>>>(W[m][2], w3h, w3l, 1024, 256);

        ushort_t* Ah = act;
        ushort_t* Al = Ah + (size_t)Mc*1024;
        ushort_t* Hh = Al + (size_t)Mc*1024;
        ushort_t* Hl = Hh + (size_t)Mc*1024;

        for (int s0 = 0; s0 < NTOK; s0 += Mc) {
            long n4 = (long)Mc*1024/4;
            k_esplit<<<dim3((unsigned)((n4 + 255)/256)), dim3(256), 0, stream>>>(
                emb + (size_t)s0*1024, Ah, Al, n4);
            if (big) {
                k_gemm_mfma256<<<dim3((Mc/256)*4), dim3(512), 0, stream>>>(
                    Ah, w1h, Hh, Hl, (unsigned)Mc*1024u, 1048576u, 1024);
                k_gemm_mfma256<<<dim3((Mc/256)*4), dim3(512), 0, stream>>>(
                    Hh, w2h, Ah, Al, (unsigned)Mc*1024u, 1048576u, 1024);
            } else {
                k_gemm_mfma<<<dim3(8, Mc/128), dim3(256), 0, stream>>>(
                    Ah, Al, w1h, w1l, Hh, Hl, nullptr, 1024);
                k_gemm_mfma<<<dim3(8, Mc/128), dim3(256), 0, stream>>>(
                    Hh, Hl, w2h, w2l, Ah, Al, nullptr, 1024);
            }
            ushort_t* seh_ptr = mfmaAssign ? SEh + ((size_t)m*NTOK + s0)*256 : nullptr;
            ushort_t* sel_ptr = mfmaAssign ? SEl + ((size_t)m*NTOK + s0)*256 : nullptr;
            k_gemm_mfma<<<dim3(2, Mc/128), dim3(256), 0, stream>>>(
                Ah, Al, w3h, w3l, seh_ptr, sel_ptr,
                out + OFF_SE + ((size_t)m*NTOK + s0)*256, 256);
        }
    }

    if (mfmaAssign) {
        k_assign_mfma<<<dim3(256, 2), dim3(256), 0, stream>>>(
            SEh, SEl, cent_h, cent_l, c2, sc, out);
    } else {
        k_assign<<<dim3(512, 2), dim3(256), 0, stream>>>(out, c2, sc, out);
    }
    k_hist   <<<dim3(128, 2), dim3(256), 0, stream>>>(sc, blockHist);
    k_scan   <<<dim3(2),      dim3(512), 0, stream>>>(blockHist, blockBase, classBase, out);
    k_scatter<<<dim3(128, 2), dim3(256), 0, stream>>>(sc, blockBase, classBase, out);
}